// Round 1
// baseline (2121.336 us; speedup 1.0000x reference)
//
#include <hip/hip_runtime.h>
#include <math.h>

#define H 64
#define W 64
#define C 256
#define O 256
#define K2 9
#define CK 2304      // C*K2
#define TP 8         // pixels per block in fused kernel
#define NB 8         // batch

// ---------------- Kernel 1: offset conv (B,27,H,W) ----------------
__global__ __launch_bounds__(256) void offset_conv_kernel(
    const float* __restrict__ x, const float* __restrict__ w_off,
    const float* __restrict__ b_off, float* __restrict__ om) {
  int idx = blockIdx.x * 256 + threadIdx.x;   // ((b*27+kc)*64+h)*64+w
  int w = idx & 63;
  int h = (idx >> 6) & 63;
  int t = idx >> 12;
  int kc = t % 27;
  int b = t / 27;
  float acc = b_off[kc];
  const float* xb = x + (size_t)b * C * H * W;
  const float* wk = w_off + kc * CK;
  for (int c = 0; c < C; ++c) {
    const float* xc = xb + c * (H * W);
    const float* wc = wk + c * 9;
#pragma unroll
    for (int dy = 0; dy < 3; ++dy) {
      int yy = h + dy - 1;
      if (yy < 0 || yy >= H) continue;
      const float* xr = xc + yy * W;
#pragma unroll
      for (int dx = 0; dx < 3; ++dx) {
        int xx = w + dx - 1;
        if (xx < 0 || xx >= W) continue;
        acc += wc[dy * 3 + dx] * xr[xx];
      }
    }
  }
  om[idx] = acc;
}

// ---------------- Kernel 2: fused sample + GEMM + BN + ReLU ----------------
__device__ __forceinline__ float samp(const float* __restrict__ xc, int y, int xx) {
  bool v = (y >= 0) && (y < H) && (xx >= 0) && (xx < W);
  int yc = min(max(y, 0), H - 1);
  int xcl = min(max(xx, 0), W - 1);
  float val = xc[yc * W + xcl];
  return v ? val : 0.0f;
}

__global__ __launch_bounds__(256) void deform_gemm_kernel(
    const float* __restrict__ x, const float* __restrict__ om,
    const float* __restrict__ weight, const float* __restrict__ bias,
    const float* __restrict__ gamma, const float* __restrict__ beta,
    const float* __restrict__ run_mean, const float* __restrict__ run_var,
    float* __restrict__ out) {
  __shared__ float cols[CK * TP];          // [ck][p]
  __shared__ float s_py[K2 * TP], s_px[K2 * TP], s_mask[K2 * TP];

  int tid = threadIdx.x;
  int pix0 = blockIdx.x * TP;              // global pixel = b*4096 + h*64 + w0
  int b = pix0 >> 12;
  int hw0 = pix0 & 4095;
  int h = hw0 >> 6;
  int w0 = hw0 & 63;                       // w0..w0+7 same row

  // phase 0: offsets + mask for the 8 pixels x 9 taps
  if (tid < K2 * TP) {
    int p = tid & 7;
    int k = tid >> 3;
    int ww = w0 + p;
    int base = ((b * 27) * H + h) * W + ww;
    float oy = om[base + k * (H * W)];
    float ox = om[base + (K2 + k) * (H * W)];
    float mv = om[base + (2 * K2 + k) * (H * W)];
    float ky = (float)(k / 3);
    float kx = (float)(k % 3);
    s_py[tid] = (float)h - 1.0f + ky + oy;
    s_px[tid] = (float)ww - 1.0f + kx + ox;
    s_mask[tid] = 1.0f / (1.0f + expf(-mv));
  }
  __syncthreads();

  // phase 1: fill cols[ck][p] with bilinear samples * mask
  const float* xb = x + (size_t)b * C * H * W;
  for (int e = tid; e < CK * TP; e += 256) {
    int p = e & 7;
    int ck = e >> 3;
    int c = ck / 9;
    int k = ck - c * 9;
    int kp = k * 8 + p;
    float py = s_py[kp], px = s_px[kp], m = s_mask[kp];
    float y0f = floorf(py), x0f = floorf(px);
    int y0 = (int)y0f, x0 = (int)x0f;
    float wy1 = py - y0f, wx1 = px - x0f;
    float wy0 = 1.0f - wy1, wx0 = 1.0f - wx1;
    const float* xc = xb + c * (H * W);
    float v00 = samp(xc, y0, x0);
    float v01 = samp(xc, y0, x0 + 1);
    float v10 = samp(xc, y0 + 1, x0);
    float v11 = samp(xc, y0 + 1, x0 + 1);
    float val = v00 * (wy0 * wx0) + v01 * (wy0 * wx1) +
                v10 * (wy1 * wx0) + v11 * (wy1 * wx1);
    cols[e] = val * m;
  }
  __syncthreads();

  // phase 2: thread o computes out[b,o,h,w0..w0+7]
  int o = tid;
  const float* wrow = weight + o * CK;
  float acc[TP];
#pragma unroll
  for (int p = 0; p < TP; ++p) acc[p] = 0.0f;

  for (int ck = 0; ck < CK; ck += 4) {
    float4 wv = *reinterpret_cast<const float4*>(wrow + ck);
    const float* wj = reinterpret_cast<const float*>(&wv);
#pragma unroll
    for (int j = 0; j < 4; ++j) {
      const float4* cp4 = reinterpret_cast<const float4*>(&cols[(ck + j) * TP]);
      float4 c0 = cp4[0];
      float4 c1 = cp4[1];
      acc[0] += wj[j] * c0.x;
      acc[1] += wj[j] * c0.y;
      acc[2] += wj[j] * c0.z;
      acc[3] += wj[j] * c0.w;
      acc[4] += wj[j] * c1.x;
      acc[5] += wj[j] * c1.y;
      acc[6] += wj[j] * c1.z;
      acc[7] += wj[j] * c1.w;
    }
  }

  float inv = gamma[o] * rsqrtf(run_var[o] + 1e-5f);
  float sh = beta[o] + (bias[o] - run_mean[o]) * inv;
  size_t obase = (((size_t)b * O + o) * H + h) * W + w0;
#pragma unroll
  for (int p = 0; p < TP; ++p) {
    float v = acc[p] * inv + sh;
    out[obase + p] = fmaxf(v, 0.0f);
  }
}

extern "C" void kernel_launch(void* const* d_in, const int* in_sizes, int n_in,
                              void* d_out, int out_size, void* d_ws, size_t ws_size,
                              hipStream_t stream) {
  const float* x        = (const float*)d_in[0];
  const float* w_off    = (const float*)d_in[1];
  const float* b_off    = (const float*)d_in[2];
  const float* weight   = (const float*)d_in[3];
  const float* bias     = (const float*)d_in[4];
  const float* gamma    = (const float*)d_in[5];
  const float* beta     = (const float*)d_in[6];
  const float* run_mean = (const float*)d_in[7];
  const float* run_var  = (const float*)d_in[8];
  float* out = (float*)d_out;
  float* om = (float*)d_ws;   // B*27*H*W floats = 3.54 MB

  // Kernel 1: offset conv
  {
    int total = NB * 27 * H * W;            // 884736
    offset_conv_kernel<<<total / 256, 256, 0, stream>>>(x, w_off, b_off, om);
  }
  // Kernel 2: fused deform-sample + GEMM + BN + ReLU
  {
    int npix = NB * H * W;                  // 32768
    deform_gemm_kernel<<<npix / TP, 256, 0, stream>>>(
        x, om, weight, bias, gamma, beta, run_mean, run_var, out);
  }
}

// Round 2
// 548.957 us; speedup vs baseline: 3.8643x; 3.8643x over previous
//
#include <hip/hip_runtime.h>
#include <math.h>

#define H 64
#define W 64
#define C 256
#define O 256
#define K2 9
#define CK 2304
#define NB 8
#define HWSZ 4096            // H*W
#define NPIX 32              // pixels per block in K2

typedef __attribute__((ext_vector_type(8))) short short8;
typedef __attribute__((ext_vector_type(4))) float floatx4;

__device__ __forceinline__ unsigned short f2bf(float f) {
  unsigned u = __builtin_bit_cast(unsigned, f);
  unsigned r = (u + 0x7fffu + ((u >> 16) & 1u)) >> 16;
  return (unsigned short)r;
}

// ---------------- Prep A: weight fp32 -> bf16 in MFMA-A-fragment layout ----
// k reordered: kn = tap*256 + c.  dest linear d = ((kstep*16+mtile)*64+lane)*8+j
// lane: m = lane&15, k_local = (lane>>4)*8 + j
__global__ __launch_bounds__(256) void prep_weight(
    const float* __restrict__ weight, unsigned short* __restrict__ wb) {
  int d0 = (blockIdx.x * 256 + threadIdx.x) * 2;
  unsigned short v[2];
#pragma unroll
  for (int e = 0; e < 2; ++e) {
    int d = d0 + e;
    int j = d & 7;
    int lane = (d >> 3) & 63;
    int mt = (d >> 9) & 15;
    int ks = d >> 13;
    int o = mt * 16 + (lane & 15);
    int kn = ks * 32 + (lane >> 4) * 8 + j;
    int tap = kn >> 8;
    int c = kn & 255;
    v[e] = f2bf(weight[o * CK + c * 9 + tap]);
  }
  unsigned pack = (unsigned)v[0] | ((unsigned)v[1] << 16);
  *reinterpret_cast<unsigned*>(wb + d0) = pack;
}

// ---------------- Prep B: folded BN scale/shift --------------------------
__global__ __launch_bounds__(256) void prep_bn(
    const float* __restrict__ bias, const float* __restrict__ gamma,
    const float* __restrict__ beta, const float* __restrict__ run_mean,
    const float* __restrict__ run_var, float* __restrict__ invsh) {
  int o = threadIdx.x;
  float inv = gamma[o] * rsqrtf(run_var[o] + 1e-5f);
  invsh[o] = inv;
  invsh[O + o] = beta[o] + (bias[o] - run_mean[o]) * inv;
}

// ---------------- Kernel 1: offset conv (B,27,H,W) -----------------------
// block = (kcg, h4, b); 256 threads: w = t&63, h = h4*4 + (t>>6)
// each thread computes 9 offset channels for one pixel: 81 FMA per 9 loads
__global__ __launch_bounds__(256) void offset_conv_kernel(
    const float* __restrict__ x, const float* __restrict__ w_off,
    const float* __restrict__ b_off, float* __restrict__ om) {
  int t = threadIdx.x;
  int w = t & 63;
  int h = blockIdx.y * 4 + (t >> 6);
  int kcg = blockIdx.x;          // 0..2 -> channels kcg*9 .. +8
  int b = blockIdx.z;

  float acc[9];
#pragma unroll
  for (int k = 0; k < 9; ++k) acc[k] = b_off[kcg * 9 + k];

  const float* xb = x + (size_t)b * C * HWSZ;
  const float* wbase = w_off + (kcg * 9) * CK;

  for (int c = 0; c < C; ++c) {
    const float* xc = xb + c * HWSZ;
    float v[9];
#pragma unroll
    for (int r = 0; r < 3; ++r) {
      int yy = h - 1 + r;
      bool rv = (yy >= 0) && (yy < H);
      int yc = min(max(yy, 0), H - 1);
#pragma unroll
      for (int d = 0; d < 3; ++d) {
        int xx = w - 1 + d;
        bool cv = (xx >= 0) && (xx < W);
        int xcl = min(max(xx, 0), W - 1);
        float val = xc[yc * W + xcl];
        v[r * 3 + d] = (rv && cv) ? val : 0.0f;
      }
    }
    const float* wr = wbase + c * 9;
#pragma unroll
    for (int k = 0; k < 9; ++k) {
      const float* w9 = wr + k * CK;
#pragma unroll
      for (int tp = 0; tp < 9; ++tp) acc[k] = fmaf(w9[tp], v[tp], acc[k]);
    }
  }

  int obase = ((b * 27 + kcg * 9) * H + h) * W + w;
#pragma unroll
  for (int k = 0; k < 9; ++k) om[obase + k * HWSZ] = acc[k];
}

// ---------------- Kernel 2: fused deform-sample + MFMA GEMM + BN + ReLU ---
// block: 32 pixels (b,h,w0..w0+31) x all 256 outputs. 256 threads = 4 waves.
// K-chunks: tap = 0..8, each chunk = 256 c's (k = tap*256 + c).
__global__ __launch_bounds__(256, 2) void deform_mfma_kernel(
    const float* __restrict__ x, const float* __restrict__ om,
    const unsigned short* __restrict__ wb, const float* __restrict__ invsh,
    float* __restrict__ out) {
  __shared__ short cols[NPIX * 256];      // [n][32 blocks of 8 bf16], XOR-swizzled
  __shared__ int sa00[NPIX], sa01[NPIX], sa10[NPIX], sa11[NPIX];
  __shared__ float sw00[NPIX], sw01[NPIX], sw10[NPIX], sw11[NPIX];

  int tid = threadIdx.x;
  int lane = tid & 63;
  int wv = tid >> 6;
  int q = lane >> 4;
  int lm = lane & 15;

  int w0 = blockIdx.x * NPIX;
  int h = blockIdx.y;
  int b = blockIdx.z;

  const float* xb = x + (size_t)b * C * HWSZ;

  floatx4 acc[4][2];
#pragma unroll
  for (int a = 0; a < 4; ++a)
#pragma unroll
    for (int u = 0; u < 2; ++u) acc[a][u] = (floatx4){0.f, 0.f, 0.f, 0.f};

  for (int tap = 0; tap < 9; ++tap) {
    __syncthreads();   // cols/coeffs free (previous chunk consumed)
    if (tid < NPIX) {
      int n = tid;
      int ww = w0 + n;
      int base = ((b * 27 + tap) * H + h) * W + ww;
      float oy = om[base];
      float ox = om[base + 9 * HWSZ];
      float mv = om[base + 18 * HWSZ];
      float m = 1.0f / (1.0f + expf(-mv));
      float py = (float)(h - 1 + (tap / 3)) + oy;
      float px = (float)(ww - 1 + (tap % 3)) + ox;
      float y0f = floorf(py), x0f = floorf(px);
      int y0 = (int)y0f, x0 = (int)x0f;
      float wy1 = py - y0f, wx1 = px - x0f;
      float wy0 = 1.0f - wy1, wx0 = 1.0f - wx1;
      bool vy0 = (y0 >= 0) && (y0 < H);
      bool vy1 = (y0 >= -1) && (y0 < H - 1);
      bool vx0 = (x0 >= 0) && (x0 < W);
      bool vx1 = (x0 >= -1) && (x0 < W - 1);
      int y0c = min(max(y0, 0), H - 1);
      int y1c = min(max(y0 + 1, 0), H - 1);
      int x0c = min(max(x0, 0), W - 1);
      int x1c = min(max(x0 + 1, 0), W - 1);
      sa00[n] = y0c * W + x0c;
      sa01[n] = y0c * W + x1c;
      sa10[n] = y1c * W + x0c;
      sa11[n] = y1c * W + x1c;
      sw00[n] = vy0 && vx0 ? wy0 * wx0 * m : 0.0f;
      sw01[n] = vy0 && vx1 ? wy0 * wx1 * m : 0.0f;
      sw10[n] = vy1 && vx0 ? wy1 * wx0 * m : 0.0f;
      sw11[n] = vy1 && vx1 ? wy1 * wx1 * m : 0.0f;
    }
    __syncthreads();

    // ---- sampling: fill cols[n][c] (bf16, swizzled) ----
    {
      int n = tid & 31;
      int cb = tid >> 5;                 // 0..7
      int A00 = sa00[n], A01 = sa01[n], A10 = sa10[n], A11 = sa11[n];
      float W00 = sw00[n], W01 = sw01[n], W10 = sw10[n], W11 = sw11[n];
#pragma unroll
      for (int i = 0; i < 4; ++i) {
        int cbase = cb * 32 + i * 8;
        short8 pk;
#pragma unroll
        for (int j = 0; j < 8; ++j) {
          int cc = cbase + j;
          int co = cc << 12;             // c * 4096
          float v00 = xb[co + A00];
          float v01 = xb[co + A01];
          float v10 = xb[co + A10];
          float v11 = xb[co + A11];
          float val = fmaf(W00, v00, fmaf(W01, v01, fmaf(W10, v10, W11 * v11)));
          pk[j] = (short)f2bf(val);
        }
        int blkL = cb * 4 + i;
        int idx = (n << 8) + (((blkL ^ n) & 31) << 3);
        *reinterpret_cast<short8*>(&cols[idx]) = pk;
      }
    }
    __syncthreads();

    // ---- MFMA: 8 k-steps over this chunk ----
#pragma unroll
    for (int s = 0; s < 8; ++s) {
      int ks = tap * 8 + s;              // global k-step 0..71
      short8 afrag[4];
#pragma unroll
      for (int a = 0; a < 4; ++a) {
        int mt = wv * 4 + a;
        afrag[a] = *reinterpret_cast<const short8*>(
            wb + (((ks * 16 + mt) * 64 + lane) << 3));
      }
      short8 bfrag[2];
#pragma unroll
      for (int u = 0; u < 2; ++u) {
        int n = u * 16 + lm;
        int blk = ((s * 4 + q) ^ n) & 31;
        bfrag[u] = *reinterpret_cast<const short8*>(&cols[(n << 8) + (blk << 3)]);
      }
#pragma unroll
      for (int a = 0; a < 4; ++a)
#pragma unroll
        for (int u = 0; u < 2; ++u)
          acc[a][u] = __builtin_amdgcn_mfma_f32_16x16x32_bf16(
              afrag[a], bfrag[u], acc[a][u], 0, 0, 0);
    }
  }

  // ---- epilogue: BN + ReLU + store ----
#pragma unroll
  for (int a = 0; a < 4; ++a) {
#pragma unroll
    for (int u = 0; u < 2; ++u) {
      int n = u * 16 + lm;
#pragma unroll
      for (int r = 0; r < 4; ++r) {
        int o = (wv * 4 + a) * 16 + q * 4 + r;
        float inv = invsh[o];
        float sh = invsh[O + o];
        float v = fmaf(acc[a][u][r], inv, sh);
        v = fmaxf(v, 0.0f);
        out[((size_t)(b * O + o)) * HWSZ + h * W + w0 + n] = v;
      }
    }
  }
}

extern "C" void kernel_launch(void* const* d_in, const int* in_sizes, int n_in,
                              void* d_out, int out_size, void* d_ws, size_t ws_size,
                              hipStream_t stream) {
  const float* x        = (const float*)d_in[0];
  const float* w_off    = (const float*)d_in[1];
  const float* b_off    = (const float*)d_in[2];
  const float* weight   = (const float*)d_in[3];
  const float* bias     = (const float*)d_in[4];
  const float* gamma    = (const float*)d_in[5];
  const float* beta     = (const float*)d_in[6];
  const float* run_mean = (const float*)d_in[7];
  const float* run_var  = (const float*)d_in[8];
  float* out = (float*)d_out;

  // workspace layout
  char* ws = (char*)d_ws;
  float* om = (float*)ws;                               // 8*27*4096 fp32 = 3538944 B
  unsigned short* wbf = (unsigned short*)(ws + 3538944); // 256*2304 bf16 = 1179648 B
  float* invsh = (float*)(ws + 3538944 + 1179648);      // 512 fp32

  prep_weight<<<(O * CK / 2 + 255) / 256, 256, 0, stream>>>(weight, wbf);
  prep_bn<<<1, 256, 0, stream>>>(bias, gamma, beta, run_mean, run_var, invsh);

  {
    dim3 grid(3, 16, NB);   // kc-group, h/4, b
    offset_conv_kernel<<<grid, 256, 0, stream>>>(x, w_off, b_off, om);
  }
  {
    dim3 grid(W / NPIX, H, NB);   // w-half, h, b
    deform_mfma_kernel<<<grid, 256, 0, stream>>>(x, om, wbf, invsh, out);
  }
}

// Round 3
// 437.710 us; speedup vs baseline: 4.8464x; 1.2542x over previous
//
#include <hip/hip_runtime.h>
#include <math.h>

#define H 64
#define W 64
#define C 256
#define O 256
#define CK 2304
#define NB 8
#define HWSZ 4096            // H*W
#define NPIX 32              // pixels per block

typedef __attribute__((ext_vector_type(8))) short short8;
typedef __attribute__((ext_vector_type(4))) float floatx4;

__device__ __forceinline__ unsigned short f2bf(float f) {
  unsigned u = __builtin_bit_cast(unsigned, f);
  unsigned r = (u + 0x7fffu + ((u >> 16) & 1u)) >> 16;
  return (unsigned short)r;
}

// ---------------- Prep A: main weight fp32 -> bf16 MFMA-A fragments -------
// k reordered: kn = tap*256 + c.  dest d = ((kstep*16+mtile)*64+lane)*8+j
__global__ __launch_bounds__(256) void prep_weight(
    const float* __restrict__ weight, unsigned short* __restrict__ wb) {
  int d0 = (blockIdx.x * 256 + threadIdx.x) * 2;
  unsigned short v[2];
#pragma unroll
  for (int e = 0; e < 2; ++e) {
    int d = d0 + e;
    int j = d & 7;
    int lane = (d >> 3) & 63;
    int mt = (d >> 9) & 15;
    int ks = d >> 13;
    int o = mt * 16 + (lane & 15);
    int kn = ks * 32 + (lane >> 4) * 8 + j;
    int tap = kn >> 8;
    int c = kn & 255;
    v[e] = f2bf(weight[o * CK + c * 9 + tap]);
  }
  unsigned pack = (unsigned)v[0] | ((unsigned)v[1] << 16);
  *reinterpret_cast<unsigned*>(wb + d0) = pack;
}

// ---------------- Prep A2: offset weight fp32 -> bf16 MFMA-A fragments ----
// M padded 27->32 (2 m-tiles).  dest d = ((kstep*2+mt)*64+lane)*8+j
__global__ __launch_bounds__(256) void prep_woff(
    const float* __restrict__ w_off, unsigned short* __restrict__ wob) {
  int d0 = (blockIdx.x * 256 + threadIdx.x) * 2;
  unsigned short v[2];
#pragma unroll
  for (int e = 0; e < 2; ++e) {
    int d = d0 + e;
    int j = d & 7;
    int lane = (d >> 3) & 63;
    int mt = (d >> 9) & 1;
    int ks = d >> 10;
    int o = mt * 16 + (lane & 15);
    int kn = ks * 32 + (lane >> 4) * 8 + j;
    int tap = kn >> 8;
    int c = kn & 255;
    v[e] = (o < 27) ? f2bf(w_off[o * CK + c * 9 + tap]) : (unsigned short)0;
  }
  unsigned pack = (unsigned)v[0] | ((unsigned)v[1] << 16);
  *reinterpret_cast<unsigned*>(wob + d0) = pack;
}

// ---------------- Prep B: folded BN scale/shift --------------------------
__global__ __launch_bounds__(256) void prep_bn(
    const float* __restrict__ bias, const float* __restrict__ gamma,
    const float* __restrict__ beta, const float* __restrict__ run_mean,
    const float* __restrict__ run_var, float* __restrict__ invsh) {
  int o = threadIdx.x;
  float inv = gamma[o] * rsqrtf(run_var[o] + 1e-5f);
  invsh[o] = inv;
  invsh[O + o] = beta[o] + (bias[o] - run_mean[o]) * inv;
}

// ---------------- Kernel 1: offset conv via MFMA --------------------------
// block: 32 pixels x 32 (27) outputs; regular im2col staged to swizzled LDS.
__global__ __launch_bounds__(256, 4) void offset_mfma_kernel(
    const float* __restrict__ x, const unsigned short* __restrict__ wob,
    const float* __restrict__ b_off, float* __restrict__ om) {
  __shared__ short cols[NPIX * 256];

  int tid = threadIdx.x;
  int lane = tid & 63;
  int wv = tid >> 6;
  int q = lane >> 4;
  int lm = lane & 15;
  int mt = wv & 1;          // m-tile 0/1
  int nt = wv >> 1;         // n-tile 0/1
  int w0 = blockIdx.x * NPIX;
  int h = blockIdx.y;
  int b = blockIdx.z;
  const float* xb = x + (size_t)b * C * HWSZ;

  floatx4 acc = (floatx4){0.f, 0.f, 0.f, 0.f};

  int n = tid & 31;
  int cb = tid >> 5;

  for (int tap = 0; tap < 9; ++tap) {
    int ty = tap / 3, tx = tap % 3;
    int yy = h - 1 + ty;
    int xx = w0 + n - 1 + tx;
    bool v = (yy >= 0) && (yy < H) && (xx >= 0) && (xx < W);
    int base = v ? yy * W + xx : 0;
    if (tap) __syncthreads();
#pragma unroll
    for (int i = 0; i < 4; ++i) {
      short8 pk;
#pragma unroll
      for (int j = 0; j < 8; ++j) {
        int c = cb * 32 + i * 8 + j;
        float val = xb[(c << 12) + base];
        pk[j] = (short)f2bf(v ? val : 0.0f);
      }
      int idx = (n << 8) + (((((cb << 2) + i) ^ n) & 31) << 3);
      *reinterpret_cast<short8*>(&cols[idx]) = pk;
    }
    __syncthreads();
#pragma unroll
    for (int s = 0; s < 8; ++s) {
      int ks = tap * 8 + s;
      short8 afrag = *reinterpret_cast<const short8*>(
          wob + (((ks * 2 + mt) * 64 + lane) << 3));
      int n2 = nt * 16 + lm;
      int blk = ((s * 4 + q) ^ n2) & 31;
      short8 bfrag = *reinterpret_cast<const short8*>(&cols[(n2 << 8) + (blk << 3)]);
      acc = __builtin_amdgcn_mfma_f32_16x16x32_bf16(afrag, bfrag, acc, 0, 0, 0);
    }
  }

  int n2 = nt * 16 + lm;
#pragma unroll
  for (int r = 0; r < 4; ++r) {
    int o = mt * 16 + q * 4 + r;
    if (o < 27)
      om[((b * 27 + o) * H + h) * W + w0 + n2] = acc[r] + b_off[o];
  }
}

// ---------------- Kernel 2: fused deform-sample + MFMA GEMM + BN + ReLU ---
__global__ __launch_bounds__(256, 4) void deform_mfma_kernel(
    const float* __restrict__ x, const float* __restrict__ om,
    const unsigned short* __restrict__ wb, const float* __restrict__ invsh,
    float* __restrict__ out) {
  __shared__ short cols[NPIX * 256];             // 16 KB, XOR-swizzled
  __shared__ int sa0[9 * NPIX], sa1[9 * NPIX], sa2[9 * NPIX], sa3[9 * NPIX];
  __shared__ float sw0[9 * NPIX], sw1[9 * NPIX], sw2[9 * NPIX], sw3[9 * NPIX];

  int tid = threadIdx.x;
  int lane = tid & 63;
  int wv = tid >> 6;
  int q = lane >> 4;
  int lm = lane & 15;

  int w0 = blockIdx.x * NPIX;
  int h = blockIdx.y;
  int b = blockIdx.z;

  const float* xb = x + (size_t)b * C * HWSZ;

  // phase -1: bilinear coeffs/addresses for ALL 9 taps x 32 pixels
  for (int e = tid; e < 9 * NPIX; e += 256) {
    int n = e & 31;
    int k = e >> 5;
    int ww = w0 + n;
    int base = ((b * 27 + k) * H + h) * W + ww;
    float oy = om[base];
    float ox = om[base + 9 * HWSZ];
    float mv = om[base + 18 * HWSZ];
    float m = 1.0f / (1.0f + __expf(-mv));
    float py = (float)(h - 1 + (k / 3)) + oy;
    float px = (float)(ww - 1 + (k % 3)) + ox;
    float y0f = floorf(py), x0f = floorf(px);
    int y0 = (int)y0f, x0 = (int)x0f;
    float wy1 = py - y0f, wx1 = px - x0f;
    float wy0 = 1.0f - wy1, wx0 = 1.0f - wx1;
    bool vy0 = (y0 >= 0) && (y0 < H);
    bool vy1 = (y0 >= -1) && (y0 < H - 1);
    bool vx0 = (x0 >= 0) && (x0 < W);
    bool vx1 = (x0 >= -1) && (x0 < W - 1);
    int y0c = min(max(y0, 0), H - 1);
    int y1c = min(max(y0 + 1, 0), H - 1);
    int x0c = min(max(x0, 0), W - 1);
    int x1c = min(max(x0 + 1, 0), W - 1);
    sa0[e] = y0c * W + x0c;
    sa1[e] = y0c * W + x1c;
    sa2[e] = y1c * W + x0c;
    sa3[e] = y1c * W + x1c;
    sw0[e] = vy0 && vx0 ? wy0 * wx0 * m : 0.0f;
    sw1[e] = vy0 && vx1 ? wy0 * wx1 * m : 0.0f;
    sw2[e] = vy1 && vx0 ? wy1 * wx0 * m : 0.0f;
    sw3[e] = vy1 && vx1 ? wy1 * wx1 * m : 0.0f;
  }
  __syncthreads();

  floatx4 acc[4][2];
#pragma unroll
  for (int a = 0; a < 4; ++a)
#pragma unroll
    for (int u = 0; u < 2; ++u) acc[a][u] = (floatx4){0.f, 0.f, 0.f, 0.f};

  int n = tid & 31;
  int cb = tid >> 5;

  for (int tap = 0; tap < 9; ++tap) {
    if (tap) __syncthreads();
    // ---- sampling: fill cols[n][c] (bf16, swizzled) ----
    {
      int ei = tap * NPIX + n;
      int A00 = sa0[ei], A01 = sa1[ei], A10 = sa2[ei], A11 = sa3[ei];
      float W00 = sw0[ei], W01 = sw1[ei], W10 = sw2[ei], W11 = sw3[ei];
#pragma unroll
      for (int i = 0; i < 4; ++i) {
        int cbase = cb * 32 + i * 8;
        short8 pk;
#pragma unroll
        for (int j = 0; j < 8; ++j) {
          int co = (cbase + j) << 12;
          float v00 = xb[co + A00];
          float v01 = xb[co + A01];
          float v10 = xb[co + A10];
          float v11 = xb[co + A11];
          float val = fmaf(W00, v00, fmaf(W01, v01, fmaf(W10, v10, W11 * v11)));
          pk[j] = (short)f2bf(val);
        }
        int idx = (n << 8) + (((((cb << 2) + i) ^ n) & 31) << 3);
        *reinterpret_cast<short8*>(&cols[idx]) = pk;
      }
    }
    __syncthreads();

    // ---- MFMA: 8 k-steps over this chunk ----
#pragma unroll
    for (int s = 0; s < 8; ++s) {
      int ks = tap * 8 + s;
      short8 afrag[4];
#pragma unroll
      for (int a = 0; a < 4; ++a) {
        int mt = wv * 4 + a;
        afrag[a] = *reinterpret_cast<const short8*>(
            wb + (((ks * 16 + mt) * 64 + lane) << 3));
      }
      short8 bfrag[2];
#pragma unroll
      for (int u = 0; u < 2; ++u) {
        int nn = u * 16 + lm;
        int blk = ((s * 4 + q) ^ nn) & 31;
        bfrag[u] = *reinterpret_cast<const short8*>(&cols[(nn << 8) + (blk << 3)]);
      }
#pragma unroll
      for (int a = 0; a < 4; ++a)
#pragma unroll
        for (int u = 0; u < 2; ++u)
          acc[a][u] = __builtin_amdgcn_mfma_f32_16x16x32_bf16(
              afrag[a], bfrag[u], acc[a][u], 0, 0, 0);
    }
  }

  // ---- epilogue: BN + ReLU + store ----
#pragma unroll
  for (int a = 0; a < 4; ++a) {
#pragma unroll
    for (int u = 0; u < 2; ++u) {
      int nn = u * 16 + lm;
#pragma unroll
      for (int r = 0; r < 4; ++r) {
        int o = (wv * 4 + a) * 16 + q * 4 + r;
        float inv = invsh[o];
        float sh = invsh[O + o];
        float v = fmaf(acc[a][u][r], inv, sh);
        v = fmaxf(v, 0.0f);
        out[((size_t)(b * O + o)) * HWSZ + h * W + w0 + nn] = v;
      }
    }
  }
}

extern "C" void kernel_launch(void* const* d_in, const int* in_sizes, int n_in,
                              void* d_out, int out_size, void* d_ws, size_t ws_size,
                              hipStream_t stream) {
  const float* x        = (const float*)d_in[0];
  const float* w_off    = (const float*)d_in[1];
  const float* b_off    = (const float*)d_in[2];
  const float* weight   = (const float*)d_in[3];
  const float* bias     = (const float*)d_in[4];
  const float* gamma    = (const float*)d_in[5];
  const float* beta     = (const float*)d_in[6];
  const float* run_mean = (const float*)d_in[7];
  const float* run_var  = (const float*)d_in[8];
  float* out = (float*)d_out;

  // workspace layout
  char* ws = (char*)d_ws;
  float* om = (float*)ws;                                  // 8*27*4096*4 = 3538944 B
  unsigned short* wbf = (unsigned short*)(ws + 3538944);   // 256*2304*2 = 1179648 B
  float* invsh = (float*)(ws + 3538944 + 1179648);         // 512*4 = 2048 B
  unsigned short* wob = (unsigned short*)(ws + 3538944 + 1179648 + 2048); // 73728*2 B

  prep_weight<<<(O * CK / 2 + 255) / 256, 256, 0, stream>>>(weight, wbf);
  prep_woff<<<(32 * CK / 2 + 255) / 256, 256, 0, stream>>>(w_off, wob);
  prep_bn<<<1, 256, 0, stream>>>(bias, gamma, beta, run_mean, run_var, invsh);

  {
    dim3 grid(W / NPIX, H, NB);
    offset_mfma_kernel<<<grid, 256, 0, stream>>>(x, wob, b_off, om);
  }
  {
    dim3 grid(W / NPIX, H, NB);
    deform_mfma_kernel<<<grid, 256, 0, stream>>>(x, om, wbf, invsh, out);
  }
}

// Round 4
// 303.005 us; speedup vs baseline: 7.0010x; 1.4446x over previous
//
#include <hip/hip_runtime.h>
#include <math.h>

#define H 64
#define W 64
#define C 256
#define O 256
#define CK 2304
#define NB 8
#define HWSZ 4096            // H*W

typedef __attribute__((ext_vector_type(8))) short short8;
typedef __attribute__((ext_vector_type(4))) float floatx4;

// swizzle: 2-way-max bank aliasing for both write and read lane maps
#define SWZ(n) ((((n) & 7) << 2) | (((n) >> 3) & 3))

__device__ __forceinline__ unsigned short f2bf(float f) {
  unsigned u = __builtin_bit_cast(unsigned, f);
  unsigned r = (u + 0x7fffu + ((u >> 16) & 1u)) >> 16;
  return (unsigned short)r;
}
__device__ __forceinline__ float bf2f(short s) {
  unsigned u = ((unsigned)(unsigned short)s) << 16;
  return __builtin_bit_cast(float, u);
}

// ---------------- Kernel T: x NCHW fp32 -> NHWC bf16 ---------------------
__global__ __launch_bounds__(256) void transpose_x(
    const float* __restrict__ x, unsigned short* __restrict__ xt) {
  __shared__ unsigned tile[64 * 132];     // [xx][c-pair], pad 132 for b128 align
  int y = blockIdx.x, b = blockIdx.y;
  int tid = threadIdx.x;
  const float* xb = x + (size_t)b * C * HWSZ + y * W;
#pragma unroll 4
  for (int it = 0; it < 32; ++it) {
    int e = tid + 256 * it;
    int xx = e & 63;
    int cp = e >> 6;                      // c-pair 0..127
    float f0 = xb[(size_t)(2 * cp) * HWSZ + xx];
    float f1 = xb[(size_t)(2 * cp + 1) * HWSZ + xx];
    tile[xx * 132 + cp] = (unsigned)f2bf(f0) | ((unsigned)f2bf(f1) << 16);
  }
  __syncthreads();
  unsigned short* xo = xt + ((size_t)(b * 64 + y) << 14);  // *64*256
#pragma unroll 2
  for (int it = 0; it < 8; ++it) {
    int e = tid + 256 * it;
    int cq = e & 31;                      // 8-c group
    int xx = e >> 5;
    uint4 v = *reinterpret_cast<const uint4*>(&tile[xx * 132 + cq * 4]);
    *reinterpret_cast<uint4*>(xo + (xx << 8) + (cq << 3)) = v;
  }
}

// ---------------- Prep A: main weight fp32 -> bf16 MFMA-A fragments -------
__global__ __launch_bounds__(256) void prep_weight(
    const float* __restrict__ weight, unsigned short* __restrict__ wb) {
  int d0 = (blockIdx.x * 256 + threadIdx.x) * 2;
  unsigned short v[2];
#pragma unroll
  for (int e = 0; e < 2; ++e) {
    int d = d0 + e;
    int j = d & 7;
    int lane = (d >> 3) & 63;
    int mt = (d >> 9) & 15;
    int ks = d >> 13;
    int o = mt * 16 + (lane & 15);
    int kn = ks * 32 + (lane >> 4) * 8 + j;
    int tap = kn >> 8;
    int c = kn & 255;
    v[e] = f2bf(weight[o * CK + c * 9 + tap]);
  }
  *reinterpret_cast<unsigned*>(wb + d0) =
      (unsigned)v[0] | ((unsigned)v[1] << 16);
}

// ---------------- Prep A2: offset weight -> bf16 A fragments (M pad 32) ---
__global__ __launch_bounds__(256) void prep_woff(
    const float* __restrict__ w_off, unsigned short* __restrict__ wob) {
  int d0 = (blockIdx.x * 256 + threadIdx.x) * 2;
  unsigned short v[2];
#pragma unroll
  for (int e = 0; e < 2; ++e) {
    int d = d0 + e;
    int j = d & 7;
    int lane = (d >> 3) & 63;
    int mt = (d >> 9) & 1;
    int ks = d >> 10;
    int o = mt * 16 + (lane & 15);
    int kn = ks * 32 + (lane >> 4) * 8 + j;
    int tap = kn >> 8;
    int c = kn & 255;
    v[e] = (o < 27) ? f2bf(w_off[o * CK + c * 9 + tap]) : (unsigned short)0;
  }
  *reinterpret_cast<unsigned*>(wob + d0) =
      (unsigned)v[0] | ((unsigned)v[1] << 16);
}

// ---------------- Prep B: folded BN scale/shift --------------------------
__global__ __launch_bounds__(256) void prep_bn(
    const float* __restrict__ bias, const float* __restrict__ gamma,
    const float* __restrict__ beta, const float* __restrict__ run_mean,
    const float* __restrict__ run_var, float* __restrict__ invsh) {
  int o = threadIdx.x;
  float inv = gamma[o] * rsqrtf(run_var[o] + 1e-5f);
  invsh[o] = inv;
  invsh[O + o] = beta[o] + (bias[o] - run_mean[o]) * inv;
}

// ---------------- Kernel 1: offset conv via MFMA (NHWC bf16 source) ------
__global__ __launch_bounds__(256, 4) void offset_mfma_kernel(
    const unsigned short* __restrict__ xt, const unsigned short* __restrict__ wob,
    const float* __restrict__ b_off, float* __restrict__ om) {
  __shared__ short cols[32 * 256];       // 16 KB

  int tid = threadIdx.x;
  int lane = tid & 63;
  int wv = tid >> 6;
  int q = lane >> 4;
  int lm = lane & 15;
  int mt = wv & 1;
  int nt = wv >> 1;
  int w0 = blockIdx.x * 32;
  int h = blockIdx.y;
  int b = blockIdx.z;
  const unsigned short* xtb = xt + ((size_t)b << 20);   // *HWSZ*256

  floatx4 acc = (floatx4){0.f, 0.f, 0.f, 0.f};
  int sn = tid >> 3;       // pixel 0..31
  int scb = tid & 7;       // c-block low bits

  for (int tap = 0; tap < 9; ++tap) {
    int yy = h - 1 + tap / 3;
    int xx = w0 + sn - 1 + tap % 3;
    bool v = (yy >= 0) && (yy < H) && (xx >= 0) && (xx < W);
    int base = v ? ((yy << 6) + xx) << 8 : 0;
    if (tap) __syncthreads();
#pragma unroll
    for (int i = 0; i < 4; ++i) {
      int cbw = (i << 3) | scb;
      short8 pk;
      if (v)
        pk = *reinterpret_cast<const short8*>(xtb + base + (cbw << 3));
      else
        pk = (short8){0, 0, 0, 0, 0, 0, 0, 0};
      int pos = (cbw ^ SWZ(sn)) & 31;
      *reinterpret_cast<short8*>(&cols[(sn << 8) + (pos << 3)]) = pk;
    }
    __syncthreads();
#pragma unroll
    for (int s = 0; s < 8; ++s) {
      int ks = tap * 8 + s;
      short8 afrag = *reinterpret_cast<const short8*>(
          wob + (((ks * 2 + mt) * 64 + lane) << 3));
      int nn = nt * 16 + lm;
      int pos = ((s * 4 + q) ^ SWZ(nn)) & 31;
      short8 bfrag = *reinterpret_cast<const short8*>(&cols[(nn << 8) + (pos << 3)]);
      acc = __builtin_amdgcn_mfma_f32_16x16x32_bf16(afrag, bfrag, acc, 0, 0, 0);
    }
  }

  int nn = nt * 16 + lm;
#pragma unroll
  for (int r = 0; r < 4; ++r) {
    int o = mt * 16 + q * 4 + r;
    if (o < 27)
      om[((b * 27 + o) * H + h) * W + w0 + nn] = acc[r] + b_off[o];
  }
}

// ---------------- Kernel 2: fused deform-sample + MFMA GEMM + BN + ReLU ---
// block = full row: 64 pixels x 256 outputs; wave = 1 n-tile x 16 m-tiles
__global__ __launch_bounds__(256, 3) void deform_mfma_kernel(
    const unsigned short* __restrict__ xt, const float* __restrict__ om,
    const unsigned short* __restrict__ wb, const float* __restrict__ invsh,
    float* __restrict__ out) {
  __shared__ short cols[64 * 256];       // 32 KB, swizzled
  __shared__ int sbase[576];
  __shared__ float s00[576], s01[576], s10[576], s11[576];

  int tid = threadIdx.x;
  int lane = tid & 63;
  int wv = tid >> 6;                     // n-tile
  int q = lane >> 4;
  int lm = lane & 15;
  int h = blockIdx.x;
  int b = blockIdx.y;
  const unsigned short* xtb = xt + ((size_t)b << 20);

  // phase -1: separable clamp-swap bilinear tables, all 9 taps x 64 pixels
  for (int e = tid; e < 576; e += 256) {
    int n = e & 63;
    int k = e >> 6;
    int base = ((b * 27 + k) * H + h) * W + n;
    float oy = om[base];
    float ox = om[base + 9 * HWSZ];
    float mv = om[base + 18 * HWSZ];
    float m = 1.0f / (1.0f + __expf(-mv));
    float py = (float)(h - 1 + k / 3) + oy;
    float px = (float)(n - 1 + k % 3) + ox;
    float yf = floorf(py), xf = floorf(px);
    int y0 = (int)yf, x0 = (int)xf;
    float fy = py - yf, fx = px - xf;
    float r0, r1; int yl;
    if (y0 >= 0 && y0 <= H - 2)      { yl = y0;    r0 = 1.f - fy; r1 = fy;       }
    else if (y0 == -1)               { yl = 0;     r0 = fy;       r1 = 0.f;      }
    else if (y0 == H - 1)            { yl = H - 2; r0 = 0.f;      r1 = 1.f - fy; }
    else                             { yl = 0;     r0 = 0.f;      r1 = 0.f;      }
    float c0, c1; int xl;
    if (x0 >= 0 && x0 <= W - 2)      { xl = x0;    c0 = 1.f - fx; c1 = fx;       }
    else if (x0 == -1)               { xl = 0;     c0 = fx;       c1 = 0.f;      }
    else if (x0 == W - 1)            { xl = W - 2; c0 = 0.f;      c1 = 1.f - fx; }
    else                             { xl = 0;     c0 = 0.f;      c1 = 0.f;      }
    r0 *= m; r1 *= m;
    sbase[e] = ((yl << 6) + xl) << 8;    // element index into xt
    s00[e] = r0 * c0; s01[e] = r0 * c1;
    s10[e] = r1 * c0; s11[e] = r1 * c1;
  }
  __syncthreads();

  floatx4 acc[16];
#pragma unroll
  for (int a = 0; a < 16; ++a) acc[a] = (floatx4){0.f, 0.f, 0.f, 0.f};

  int sn = tid >> 2;        // pixel 0..63
  int scb = tid & 3;        // c-block low bits

  for (int tap = 0; tap < 9; ++tap) {
    if (tap) __syncthreads();
    // ---- sampling: 4 coalesced corner loads per c-block of 8 ----
    {
      int ei = tap * 64 + sn;
      int base = sbase[ei];
      float w00 = s00[ei], w01 = s01[ei], w10 = s10[ei], w11 = s11[ei];
      const unsigned short* p = xtb + base;
#pragma unroll
      for (int i = 0; i < 8; ++i) {
        int cbw = (i << 2) | scb;
        int co = cbw << 3;
        short8 f00 = *reinterpret_cast<const short8*>(p + co);
        short8 f01 = *reinterpret_cast<const short8*>(p + 256 + co);
        short8 f10 = *reinterpret_cast<const short8*>(p + 16384 + co);
        short8 f11 = *reinterpret_cast<const short8*>(p + 16640 + co);
        short8 pk;
#pragma unroll
        for (int j = 0; j < 8; ++j) {
          float v = w00 * bf2f(f00[j]) + w01 * bf2f(f01[j]) +
                    w10 * bf2f(f10[j]) + w11 * bf2f(f11[j]);
          pk[j] = (short)f2bf(v);
        }
        int pos = (cbw ^ SWZ(sn)) & 31;
        *reinterpret_cast<short8*>(&cols[(sn << 8) + (pos << 3)]) = pk;
      }
    }
    __syncthreads();

    // ---- MFMA: 8 k-steps, 16 m-tiles per wave ----
#pragma unroll
    for (int s = 0; s < 8; ++s) {
      int ks = tap * 8 + s;
      int nn = wv * 16 + lm;
      int pos = ((s * 4 + q) ^ SWZ(nn)) & 31;
      short8 bfrag = *reinterpret_cast<const short8*>(&cols[(nn << 8) + (pos << 3)]);
      const unsigned short* wp = wb + (((size_t)ks * 16 * 64 + lane) << 3);
#pragma unroll
      for (int a = 0; a < 16; ++a) {
        short8 afrag = *reinterpret_cast<const short8*>(wp + (a << 9));
        acc[a] = __builtin_amdgcn_mfma_f32_16x16x32_bf16(afrag, bfrag, acc[a], 0, 0, 0);
      }
    }
  }

  // ---- epilogue: BN + ReLU + store ----
  int nn = wv * 16 + lm;
#pragma unroll
  for (int a = 0; a < 16; ++a) {
#pragma unroll
    for (int r = 0; r < 4; ++r) {
      int o = a * 16 + q * 4 + r;
      float v = fmaf(acc[a][r], invsh[o], invsh[O + o]);
      out[((size_t)(b * O + o)) * HWSZ + h * W + nn] = fmaxf(v, 0.0f);
    }
  }
}

extern "C" void kernel_launch(void* const* d_in, const int* in_sizes, int n_in,
                              void* d_out, int out_size, void* d_ws, size_t ws_size,
                              hipStream_t stream) {
  const float* x        = (const float*)d_in[0];
  const float* w_off    = (const float*)d_in[1];
  const float* b_off    = (const float*)d_in[2];
  const float* weight   = (const float*)d_in[3];
  const float* bias     = (const float*)d_in[4];
  const float* gamma    = (const float*)d_in[5];
  const float* beta     = (const float*)d_in[6];
  const float* run_mean = (const float*)d_in[7];
  const float* run_var  = (const float*)d_in[8];
  float* out = (float*)d_out;

  // workspace layout (~21.65 MB)
  char* ws = (char*)d_ws;
  unsigned short* xt = (unsigned short*)ws;                    // 16777216 B
  float* om  = (float*)(ws + 16777216);                        // 3538944 B
  unsigned short* wbf = (unsigned short*)(ws + 20316160);      // 1179648 B
  unsigned short* wob = (unsigned short*)(ws + 21495808);      // 147456 B
  float* invsh = (float*)(ws + 21643264);                      // 2048 B

  {
    dim3 grid(H, NB);
    transpose_x<<<grid, 256, 0, stream>>>(x, xt);
  }
  prep_weight<<<O * CK / 512, 256, 0, stream>>>(weight, wbf);
  prep_woff<<<32 * CK / 512, 256, 0, stream>>>(w_off, wob);
  prep_bn<<<1, 256, 0, stream>>>(bias, gamma, beta, run_mean, run_var, invsh);

  {
    dim3 grid(2, H, NB);
    offset_mfma_kernel<<<grid, 256, 0, stream>>>(xt, wob, b_off, om);
  }
  {
    dim3 grid(H, NB);
    deform_mfma_kernel<<<grid, 256, 0, stream>>>(xt, om, wbf, invsh, out);
  }
}

// Round 5
// 260.144 us; speedup vs baseline: 8.1545x; 1.1648x over previous
//
#include <hip/hip_runtime.h>
#include <math.h>

#define H 64
#define W 64
#define C 256
#define O 256
#define CK 2304
#define NB 8
#define HWSZ 4096            // H*W

typedef __attribute__((ext_vector_type(8))) short short8;
typedef __attribute__((ext_vector_type(4))) float floatx4;

// swizzle: 2-way-max bank aliasing for both write and read lane maps
#define SWZ(n) ((((n) & 7) << 2) | (((n) >> 3) & 3))

__device__ __forceinline__ unsigned short f2bf(float f) {
  unsigned u = __builtin_bit_cast(unsigned, f);
  unsigned r = (u + 0x7fffu + ((u >> 16) & 1u)) >> 16;
  return (unsigned short)r;
}
__device__ __forceinline__ float bf2f(short s) {
  unsigned u = ((unsigned)(unsigned short)s) << 16;
  return __builtin_bit_cast(float, u);
}

// ---------------- Kernel T: x NCHW fp32 -> NHWC bf16 ---------------------
__global__ __launch_bounds__(256) void transpose_x(
    const float* __restrict__ x, unsigned short* __restrict__ xt) {
  __shared__ unsigned tile[64 * 132];     // [xx][c-pair], pad 132 for b128 align
  int y = blockIdx.x, b = blockIdx.y;
  int tid = threadIdx.x;
  const float* xb = x + (size_t)b * C * HWSZ + y * W;
#pragma unroll 4
  for (int it = 0; it < 32; ++it) {
    int e = tid + 256 * it;
    int xx = e & 63;
    int cp = e >> 6;                      // c-pair 0..127
    float f0 = xb[(size_t)(2 * cp) * HWSZ + xx];
    float f1 = xb[(size_t)(2 * cp + 1) * HWSZ + xx];
    tile[xx * 132 + cp] = (unsigned)f2bf(f0) | ((unsigned)f2bf(f1) << 16);
  }
  __syncthreads();
  unsigned short* xo = xt + ((size_t)(b * 64 + y) << 14);  // *64*256
#pragma unroll 2
  for (int it = 0; it < 8; ++it) {
    int e = tid + 256 * it;
    int cq = e & 31;                      // 8-c group
    int xx = e >> 5;
    uint4 v = *reinterpret_cast<const uint4*>(&tile[xx * 132 + cq * 4]);
    *reinterpret_cast<uint4*>(xo + (xx << 8) + (cq << 3)) = v;
  }
}

// ---------------- Prep A: main weight fp32 -> bf16 MFMA-A fragments -------
__global__ __launch_bounds__(256) void prep_weight(
    const float* __restrict__ weight, unsigned short* __restrict__ wb) {
  int d0 = (blockIdx.x * 256 + threadIdx.x) * 2;
  unsigned short v[2];
#pragma unroll
  for (int e = 0; e < 2; ++e) {
    int d = d0 + e;
    int j = d & 7;
    int lane = (d >> 3) & 63;
    int mt = (d >> 9) & 15;
    int ks = d >> 13;
    int o = mt * 16 + (lane & 15);
    int kn = ks * 32 + (lane >> 4) * 8 + j;
    int tap = kn >> 8;
    int c = kn & 255;
    v[e] = f2bf(weight[o * CK + c * 9 + tap]);
  }
  *reinterpret_cast<unsigned*>(wb + d0) =
      (unsigned)v[0] | ((unsigned)v[1] << 16);
}

// ---------------- Prep A2: offset weight -> bf16 A fragments (M pad 32) ---
__global__ __launch_bounds__(256) void prep_woff(
    const float* __restrict__ w_off, unsigned short* __restrict__ wob) {
  int d0 = (blockIdx.x * 256 + threadIdx.x) * 2;
  unsigned short v[2];
#pragma unroll
  for (int e = 0; e < 2; ++e) {
    int d = d0 + e;
    int j = d & 7;
    int lane = (d >> 3) & 63;
    int mt = (d >> 9) & 1;
    int ks = d >> 10;
    int o = mt * 16 + (lane & 15);
    int kn = ks * 32 + (lane >> 4) * 8 + j;
    int tap = kn >> 8;
    int c = kn & 255;
    v[e] = (o < 27) ? f2bf(w_off[o * CK + c * 9 + tap]) : (unsigned short)0;
  }
  *reinterpret_cast<unsigned*>(wob + d0) =
      (unsigned)v[0] | ((unsigned)v[1] << 16);
}

// ---------------- Prep B: folded BN scale/shift --------------------------
__global__ __launch_bounds__(256) void prep_bn(
    const float* __restrict__ bias, const float* __restrict__ gamma,
    const float* __restrict__ beta, const float* __restrict__ run_mean,
    const float* __restrict__ run_var, float* __restrict__ invsh) {
  int o = threadIdx.x;
  float inv = gamma[o] * rsqrtf(run_var[o] + 1e-5f);
  invsh[o] = inv;
  invsh[O + o] = beta[o] + (bias[o] - run_mean[o]) * inv;
}

// ---------------- Kernel 1: offset conv via MFMA, barrier-free -----------
// B-fragments loaded DIRECTLY from NHWC xt (regular im2col); no LDS.
// block = 64 pixels (full row) x 32 outs; wave = 16 px x 2 m-tiles.
__global__ __launch_bounds__(256) void offset_mfma_kernel(
    const unsigned short* __restrict__ xt, const unsigned short* __restrict__ wob,
    const float* __restrict__ b_off, float* __restrict__ om) {
  int tid = threadIdx.x;
  int lane = tid & 63;
  int wv = tid >> 6;          // n-tile 0..3
  int q = lane >> 4;
  int lm = lane & 15;
  int h = blockIdx.x;
  int b = blockIdx.y;
  const unsigned short* xtb = xt + ((size_t)b << 20);

  floatx4 acc[2];
  acc[0] = (floatx4){0.f, 0.f, 0.f, 0.f};
  acc[1] = (floatx4){0.f, 0.f, 0.f, 0.f};

  int px = wv * 16 + lm;      // pixel 0..63
  for (int tap = 0; tap < 9; ++tap) {
    int yy = h - 1 + tap / 3;
    int xx = px - 1 + tap % 3;
    bool v = (yy >= 0) && (yy < H) && (xx >= 0) && (xx < W);
    const unsigned short* bp =
        xtb + ((((yy & 63) << 6) + (xx & 63)) << 8) + q * 8;
#pragma unroll
    for (int s = 0; s < 8; ++s) {
      int ks = tap * 8 + s;
      short8 bfrag;
      if (v)
        bfrag = *reinterpret_cast<const short8*>(bp + s * 32);
      else
        bfrag = (short8){0, 0, 0, 0, 0, 0, 0, 0};
#pragma unroll
      for (int mt = 0; mt < 2; ++mt) {
        short8 afrag = *reinterpret_cast<const short8*>(
            wob + (((ks * 2 + mt) * 64 + lane) << 3));
        acc[mt] = __builtin_amdgcn_mfma_f32_16x16x32_bf16(afrag, bfrag, acc[mt], 0, 0, 0);
      }
    }
  }
#pragma unroll
  for (int mt = 0; mt < 2; ++mt)
#pragma unroll
    for (int r = 0; r < 4; ++r) {
      int o = mt * 16 + q * 4 + r;
      if (o < 27)
        om[((b * 27 + o) * H + h) * W + px] = acc[mt][r] + b_off[o];
    }
}

// ---------------- Kernel 2: fused deform-sample + MFMA GEMM + BN + ReLU ---
// block = 64 pixels x 256 outputs; wave = 4 n-tiles x 4 m-tiles
// (each A-fragment read by exactly ONE wave -> 4x less L1/VMEM A-traffic)
__global__ __launch_bounds__(256, 3) void deform_mfma_kernel(
    const unsigned short* __restrict__ xt, const float* __restrict__ om,
    const unsigned short* __restrict__ wb, const float* __restrict__ invsh,
    float* __restrict__ out) {
  __shared__ short cols[64 * 256];       // 32 KB, swizzled
  __shared__ int sbase[576];
  __shared__ float s00[576], s01[576], s10[576], s11[576];

  int tid = threadIdx.x;
  int lane = tid & 63;
  int wv = tid >> 6;                     // m-group: m-tiles wv*4..wv*4+3
  int q = lane >> 4;
  int lm = lane & 15;
  int h = blockIdx.x;
  int b = blockIdx.y;
  const unsigned short* xtb = xt + ((size_t)b << 20);

  // phase -1: separable clamp-swap bilinear tables, all 9 taps x 64 pixels
  for (int e = tid; e < 576; e += 256) {
    int n = e & 63;
    int k = e >> 6;
    int base = ((b * 27 + k) * H + h) * W + n;
    float oy = om[base];
    float ox = om[base + 9 * HWSZ];
    float mv = om[base + 18 * HWSZ];
    float m = 1.0f / (1.0f + __expf(-mv));
    float py = (float)(h - 1 + k / 3) + oy;
    float px = (float)(n - 1 + k % 3) + ox;
    float yf = floorf(py), xf = floorf(px);
    int y0 = (int)yf, x0 = (int)xf;
    float fy = py - yf, fx = px - xf;
    float r0, r1; int yl;
    if (y0 >= 0 && y0 <= H - 2)      { yl = y0;    r0 = 1.f - fy; r1 = fy;       }
    else if (y0 == -1)               { yl = 0;     r0 = fy;       r1 = 0.f;      }
    else if (y0 == H - 1)            { yl = H - 2; r0 = 0.f;      r1 = 1.f - fy; }
    else                             { yl = 0;     r0 = 0.f;      r1 = 0.f;      }
    float c0, c1; int xl;
    if (x0 >= 0 && x0 <= W - 2)      { xl = x0;    c0 = 1.f - fx; c1 = fx;       }
    else if (x0 == -1)               { xl = 0;     c0 = fx;       c1 = 0.f;      }
    else if (x0 == W - 1)            { xl = W - 2; c0 = 0.f;      c1 = 1.f - fx; }
    else                             { xl = 0;     c0 = 0.f;      c1 = 0.f;      }
    r0 *= m; r1 *= m;
    sbase[e] = ((yl << 6) + xl) << 8;    // element index into xt
    s00[e] = r0 * c0; s01[e] = r0 * c1;
    s10[e] = r1 * c0; s11[e] = r1 * c1;
  }
  __syncthreads();

  floatx4 acc[4][4];                     // [m-tile a][n-tile u]
#pragma unroll
  for (int a = 0; a < 4; ++a)
#pragma unroll
    for (int u = 0; u < 4; ++u) acc[a][u] = (floatx4){0.f, 0.f, 0.f, 0.f};

  int sn = tid >> 2;        // pixel 0..63
  int scb = tid & 3;        // c-block low bits

  for (int tap = 0; tap < 9; ++tap) {
    if (tap) __syncthreads();
    // ---- sampling: 4 coalesced corner loads per c-block of 8 ----
    {
      int ei = tap * 64 + sn;
      int base = sbase[ei];
      float w00 = s00[ei], w01 = s01[ei], w10 = s10[ei], w11 = s11[ei];
      const unsigned short* p = xtb + base;
#pragma unroll
      for (int i = 0; i < 8; ++i) {
        int cbw = (i << 2) | scb;
        int co = cbw << 3;
        short8 f00 = *reinterpret_cast<const short8*>(p + co);
        short8 f01 = *reinterpret_cast<const short8*>(p + 256 + co);
        short8 f10 = *reinterpret_cast<const short8*>(p + 16384 + co);
        short8 f11 = *reinterpret_cast<const short8*>(p + 16640 + co);
        short8 pk;
#pragma unroll
        for (int j = 0; j < 8; ++j) {
          float v = w00 * bf2f(f00[j]) + w01 * bf2f(f01[j]) +
                    w10 * bf2f(f10[j]) + w11 * bf2f(f11[j]);
          pk[j] = (short)f2bf(v);
        }
        int pos = (cbw ^ SWZ(sn)) & 31;
        *reinterpret_cast<short8*>(&cols[(sn << 8) + (pos << 3)]) = pk;
      }
    }
    __syncthreads();

    // ---- MFMA: 8 k-steps, 4 m-tiles x 4 n-tiles per wave ----
#pragma unroll
    for (int s = 0; s < 8; ++s) {
      int ks = tap * 8 + s;
      short8 afrag[4];
#pragma unroll
      for (int a = 0; a < 4; ++a)
        afrag[a] = *reinterpret_cast<const short8*>(
            wb + (((ks * 16 + wv * 4 + a) * 64 + lane) << 3));
      short8 bfrag[4];
#pragma unroll
      for (int u = 0; u < 4; ++u) {
        int nn = u * 16 + lm;
        int pos = ((s * 4 + q) ^ SWZ(nn)) & 31;
        bfrag[u] = *reinterpret_cast<const short8*>(&cols[(nn << 8) + (pos << 3)]);
      }
#pragma unroll
      for (int a = 0; a < 4; ++a)
#pragma unroll
        for (int u = 0; u < 4; ++u)
          acc[a][u] = __builtin_amdgcn_mfma_f32_16x16x32_bf16(
              afrag[a], bfrag[u], acc[a][u], 0, 0, 0);
    }
  }

  // ---- epilogue: BN + ReLU + store ----
#pragma unroll
  for (int a = 0; a < 4; ++a) {
#pragma unroll
    for (int u = 0; u < 4; ++u) {
      int nn = u * 16 + lm;
#pragma unroll
      for (int r = 0; r < 4; ++r) {
        int o = (wv * 4 + a) * 16 + q * 4 + r;
        float v = fmaf(acc[a][u][r], invsh[o], invsh[O + o]);
        out[((size_t)(b * O + o)) * HWSZ + h * W + nn] = fmaxf(v, 0.0f);
      }
    }
  }
}

extern "C" void kernel_launch(void* const* d_in, const int* in_sizes, int n_in,
                              void* d_out, int out_size, void* d_ws, size_t ws_size,
                              hipStream_t stream) {
  const float* x        = (const float*)d_in[0];
  const float* w_off    = (const float*)d_in[1];
  const float* b_off    = (const float*)d_in[2];
  const float* weight   = (const float*)d_in[3];
  const float* bias     = (const float*)d_in[4];
  const float* gamma    = (const float*)d_in[5];
  const float* beta     = (const float*)d_in[6];
  const float* run_mean = (const float*)d_in[7];
  const float* run_var  = (const float*)d_in[8];
  float* out = (float*)d_out;

  // workspace layout (~21.65 MB)
  char* ws = (char*)d_ws;
  unsigned short* xt = (unsigned short*)ws;                    // 16777216 B
  float* om  = (float*)(ws + 16777216);                        // 3538944 B
  unsigned short* wbf = (unsigned short*)(ws + 20316160);      // 1179648 B
  unsigned short* wob = (unsigned short*)(ws + 21495808);      // 147456 B
  float* invsh = (float*)(ws + 21643264);                      // 2048 B

  {
    dim3 grid(H, NB);
    transpose_x<<<grid, 256, 0, stream>>>(x, xt);
  }
  prep_weight<<<O * CK / 512, 256, 0, stream>>>(weight, wbf);
  prep_woff<<<32 * CK / 512, 256, 0, stream>>>(w_off, wob);
  prep_bn<<<1, 256, 0, stream>>>(bias, gamma, beta, run_mean, run_var, invsh);

  {
    dim3 grid(H, NB);
    offset_mfma_kernel<<<grid, 256, 0, stream>>>(xt, wob, b_off, om);
  }
  {
    dim3 grid(H, NB);
    deform_mfma_kernel<<<grid, 256, 0, stream>>>(xt, om, wbf, invsh, out);
  }
}

// Round 6
// 212.502 us; speedup vs baseline: 9.9827x; 1.2242x over previous
//
#include <hip/hip_runtime.h>
#include <math.h>

#define H 64
#define W 64
#define C 256
#define O 256
#define CK 2304
#define NB 8
#define HWSZ 4096            // H*W

typedef __attribute__((ext_vector_type(8))) short short8;
typedef __attribute__((ext_vector_type(4))) float floatx4;

// swizzle giving uniform bank-group coverage in every 16-lane b128 phase
// for both the sampling-write map and the MFMA-read map (see R6 notes).
#define FSWZ(n) ((((n) & 3) << 1) | (((n) >> 2) & 1))

__device__ __forceinline__ unsigned short f2bf(float f) {
  unsigned u = __builtin_bit_cast(unsigned, f);
  unsigned r = (u + 0x7fffu + ((u >> 16) & 1u)) >> 16;
  return (unsigned short)r;
}
__device__ __forceinline__ float bf2f(short s) {
  unsigned u = ((unsigned)(unsigned short)s) << 16;
  return __builtin_bit_cast(float, u);
}

// ---------------- Kernel T: x NCHW fp32 -> NHWC bf16 ---------------------
// grid (b, y, cg): XCD affinity by b; cg = channel half (128 ch).
__global__ __launch_bounds__(256) void transpose_x(
    const float* __restrict__ x, unsigned short* __restrict__ xt) {
  __shared__ unsigned tile[64 * 65];      // [c-pair][xx], stride 65 (2-way max)
  int b = blockIdx.x, y = blockIdx.y, cg = blockIdx.z;
  int tid = threadIdx.x;
  const float* xb = x + ((size_t)b * C + cg * 128) * HWSZ + y * W;
#pragma unroll 4
  for (int it = 0; it < 16; ++it) {
    int e = tid + 256 * it;
    int xx = e & 63;
    int cp = e >> 6;                      // local c-pair 0..63
    float f0 = xb[(size_t)(2 * cp) * HWSZ + xx];
    float f1 = xb[(size_t)(2 * cp + 1) * HWSZ + xx];
    tile[cp * 65 + xx] = (unsigned)f2bf(f0) | ((unsigned)f2bf(f1) << 16);
  }
  __syncthreads();
  unsigned short* xo = xt + ((size_t)(b * 64 + y) << 14) + cg * 128;
#pragma unroll
  for (int it = 0; it < 4; ++it) {
    int e = tid + 256 * it;
    int cq = e & 15;                      // c-octet within the 128-ch half
    int xx = e >> 4;
    unsigned u0 = tile[(cq * 4 + 0) * 65 + xx];
    unsigned u1 = tile[(cq * 4 + 1) * 65 + xx];
    unsigned u2 = tile[(cq * 4 + 2) * 65 + xx];
    unsigned u3 = tile[(cq * 4 + 3) * 65 + xx];
    uint4 v = {u0, u1, u2, u3};
    *reinterpret_cast<uint4*>(xo + (xx << 8) + (cq << 3)) = v;
  }
}

// ---------------- Prep A: main weight fp32 -> bf16 MFMA-A fragments -------
__global__ __launch_bounds__(256) void prep_weight(
    const float* __restrict__ weight, unsigned short* __restrict__ wb) {
  int d0 = (blockIdx.x * 256 + threadIdx.x) * 2;
  unsigned short v[2];
#pragma unroll
  for (int e = 0; e < 2; ++e) {
    int d = d0 + e;
    int j = d & 7;
    int lane = (d >> 3) & 63;
    int mt = (d >> 9) & 15;
    int ks = d >> 13;
    int o = mt * 16 + (lane & 15);
    int kn = ks * 32 + (lane >> 4) * 8 + j;
    int tap = kn >> 8;
    int c = kn & 255;
    v[e] = f2bf(weight[o * CK + c * 9 + tap]);
  }
  *reinterpret_cast<unsigned*>(wb + d0) =
      (unsigned)v[0] | ((unsigned)v[1] << 16);
}

// ---------------- Prep A2: offset weight -> bf16 A fragments (M pad 32) ---
__global__ __launch_bounds__(256) void prep_woff(
    const float* __restrict__ w_off, unsigned short* __restrict__ wob) {
  int d0 = (blockIdx.x * 256 + threadIdx.x) * 2;
  unsigned short v[2];
#pragma unroll
  for (int e = 0; e < 2; ++e) {
    int d = d0 + e;
    int j = d & 7;
    int lane = (d >> 3) & 63;
    int mt = (d >> 9) & 1;
    int ks = d >> 10;
    int o = mt * 16 + (lane & 15);
    int kn = ks * 32 + (lane >> 4) * 8 + j;
    int tap = kn >> 8;
    int c = kn & 255;
    v[e] = (o < 27) ? f2bf(w_off[o * CK + c * 9 + tap]) : (unsigned short)0;
  }
  *reinterpret_cast<unsigned*>(wob + d0) =
      (unsigned)v[0] | ((unsigned)v[1] << 16);
}

// ---------------- Prep B: folded BN scale/shift --------------------------
__global__ __launch_bounds__(256) void prep_bn(
    const float* __restrict__ bias, const float* __restrict__ gamma,
    const float* __restrict__ beta, const float* __restrict__ run_mean,
    const float* __restrict__ run_var, float* __restrict__ invsh) {
  int o = threadIdx.x;
  float inv = gamma[o] * rsqrtf(run_var[o] + 1e-5f);
  invsh[o] = inv;
  invsh[O + o] = beta[o] + (bias[o] - run_mean[o]) * inv;
}

// ---------------- Kernel 1: offset conv via MFMA, barrier-free -----------
// grid (b, h, half): 1024 blocks, 32 px x 32 outs, wave = 16 px x 1 m-tile
__global__ __launch_bounds__(256, 4) void offset_mfma_kernel(
    const unsigned short* __restrict__ xt, const unsigned short* __restrict__ wob,
    const float* __restrict__ b_off, float* __restrict__ om) {
  int tid = threadIdx.x;
  int lane = tid & 63;
  int wvid = tid >> 6;
  int nt = wvid & 1;
  int mt = wvid >> 1;
  int q = lane >> 4;
  int lm = lane & 15;
  int b = blockIdx.x;
  int h = blockIdx.y;
  int half = blockIdx.z;
  const unsigned short* xtb = xt + ((size_t)b << 20);

  floatx4 acc = (floatx4){0.f, 0.f, 0.f, 0.f};
  int px = half * 32 + nt * 16 + lm;

  for (int tap = 0; tap < 9; ++tap) {
    int yy = h - 1 + tap / 3;
    int xx = px - 1 + tap % 3;
    bool v = (yy >= 0) && (yy < H) && (xx >= 0) && (xx < W);
    const unsigned short* bp =
        xtb + ((((yy & 63) << 6) + (xx & 63)) << 8) + q * 8;
#pragma unroll
    for (int s = 0; s < 8; ++s) {
      int ks = tap * 8 + s;
      short8 bfrag;
      if (v)
        bfrag = *reinterpret_cast<const short8*>(bp + s * 32);
      else
        bfrag = (short8){0, 0, 0, 0, 0, 0, 0, 0};
      short8 afrag = *reinterpret_cast<const short8*>(
          wob + (((ks * 2 + mt) * 64 + lane) << 3));
      acc = __builtin_amdgcn_mfma_f32_16x16x32_bf16(afrag, bfrag, acc, 0, 0, 0);
    }
  }
#pragma unroll
  for (int r = 0; r < 4; ++r) {
    int o = mt * 16 + q * 4 + r;
    if (o < 27)
      om[((b * 27 + o) * H + h) * W + px] = acc[r] + b_off[o];
  }
}

// ---------------- Kernel 2: fused deform-sample + MFMA GEMM + BN + ReLU ---
// grid (b, h): 512 blocks x 512 threads (8 waves).  Block = 64 px x 256 out.
// Wave = 4 m-tiles x 2 n-tiles; A-frags shared by wave pairs via L1.
__global__ __launch_bounds__(512, 4) void deform_mfma_kernel(
    const unsigned short* __restrict__ xt, const float* __restrict__ om,
    const unsigned short* __restrict__ wb, const float* __restrict__ invsh,
    float* __restrict__ out) {
  __shared__ short cols[64 * 256];       // 32 KB, FSWZ-swizzled
  __shared__ int sbase[576];
  __shared__ float s00[576], s01[576], s10[576], s11[576];

  int tid = threadIdx.x;
  int lane = tid & 63;
  int wvid = tid >> 6;                   // 0..7
  int mg = wvid >> 1;                    // m-group: m-tiles mg*4..mg*4+3
  int nh = wvid & 1;                     // n-half: n-tiles nh*2, nh*2+1
  int q = lane >> 4;
  int lm = lane & 15;
  int b = blockIdx.x;
  int h = blockIdx.y;
  const unsigned short* xtb = xt + ((size_t)b << 20);

  // phase -1: separable clamp-swap bilinear tables, all 9 taps x 64 pixels
  for (int e = tid; e < 576; e += 512) {
    int n = e & 63;
    int k = e >> 6;
    int base = ((b * 27 + k) * H + h) * W + n;
    float oy = om[base];
    float ox = om[base + 9 * HWSZ];
    float mv = om[base + 18 * HWSZ];
    float m = 1.0f / (1.0f + __expf(-mv));
    float py = (float)(h - 1 + k / 3) + oy;
    float px = (float)(n - 1 + k % 3) + ox;
    float yf = floorf(py), xf = floorf(px);
    int y0 = (int)yf, x0 = (int)xf;
    float fy = py - yf, fx = px - xf;
    float r0, r1; int yl;
    if (y0 >= 0 && y0 <= H - 2)      { yl = y0;    r0 = 1.f - fy; r1 = fy;       }
    else if (y0 == -1)               { yl = 0;     r0 = fy;       r1 = 0.f;      }
    else if (y0 == H - 1)            { yl = H - 2; r0 = 0.f;      r1 = 1.f - fy; }
    else                             { yl = 0;     r0 = 0.f;      r1 = 0.f;      }
    float c0, c1; int xl;
    if (x0 >= 0 && x0 <= W - 2)      { xl = x0;    c0 = 1.f - fx; c1 = fx;       }
    else if (x0 == -1)               { xl = 0;     c0 = fx;       c1 = 0.f;      }
    else if (x0 == W - 1)            { xl = W - 2; c0 = 0.f;      c1 = 1.f - fx; }
    else                             { xl = 0;     c0 = 0.f;      c1 = 0.f;      }
    r0 *= m; r1 *= m;
    sbase[e] = ((yl << 6) + xl) << 8;    // element index into xt
    s00[e] = r0 * c0; s01[e] = r0 * c1;
    s10[e] = r1 * c0; s11[e] = r1 * c1;
  }
  __syncthreads();

  floatx4 acc[4][2];                     // [m within group][n within half]
#pragma unroll
  for (int a = 0; a < 4; ++a)
#pragma unroll
    for (int u = 0; u < 2; ++u) acc[a][u] = (floatx4){0.f, 0.f, 0.f, 0.f};

  int sn = tid >> 3;        // pixel 0..63
  int scb = tid & 7;        // c-block low bits

  for (int tap = 0; tap < 9; ++tap) {
    if (tap) __syncthreads();
    // ---- sampling: 4 coalesced corner loads per c-block of 8 ----
    {
      int ei = tap * 64 + sn;
      int base = sbase[ei];
      float w00 = s00[ei], w01 = s01[ei], w10 = s10[ei], w11 = s11[ei];
      const unsigned short* p = xtb + base;
#pragma unroll
      for (int i = 0; i < 4; ++i) {
        int cbw = (i << 3) | scb;
        int co = cbw << 3;
        short8 f00 = *reinterpret_cast<const short8*>(p + co);
        short8 f01 = *reinterpret_cast<const short8*>(p + 256 + co);
        short8 f10 = *reinterpret_cast<const short8*>(p + 16384 + co);
        short8 f11 = *reinterpret_cast<const short8*>(p + 16640 + co);
        short8 pk;
#pragma unroll
        for (int j = 0; j < 8; ++j) {
          float v = w00 * bf2f(f00[j]) + w01 * bf2f(f01[j]) +
                    w10 * bf2f(f10[j]) + w11 * bf2f(f11[j]);
          pk[j] = (short)f2bf(v);
        }
        int pos = (cbw ^ FSWZ(sn)) & 31;
        *reinterpret_cast<short8*>(&cols[(sn << 8) + (pos << 3)]) = pk;
      }
    }
    __syncthreads();

    // ---- MFMA: 8 k-steps, 4 m-tiles x 2 n-tiles per wave ----
#pragma unroll
    for (int s = 0; s < 8; ++s) {
      int ks = tap * 8 + s;
      short8 afrag[4];
#pragma unroll
      for (int a = 0; a < 4; ++a)
        afrag[a] = *reinterpret_cast<const short8*>(
            wb + (((ks * 16 + mg * 4 + a) * 64 + lane) << 3));
      short8 bfrag[2];
#pragma unroll
      for (int u = 0; u < 2; ++u) {
        int nn = (nh * 2 + u) * 16 + lm;
        int pos = ((s * 4 + q) ^ FSWZ(nn)) & 31;
        bfrag[u] = *reinterpret_cast<const short8*>(&cols[(nn << 8) + (pos << 3)]);
      }
#pragma unroll
      for (int a = 0; a < 4; ++a)
#pragma unroll
        for (int u = 0; u < 2; ++u)
          acc[a][u] = __builtin_amdgcn_mfma_f32_16x16x32_bf16(
              afrag[a], bfrag[u], acc[a][u], 0, 0, 0);
    }
  }

  // ---- epilogue: BN + ReLU + store ----
#pragma unroll
  for (int a = 0; a < 4; ++a) {
#pragma unroll
    for (int u = 0; u < 2; ++u) {
      int nn = (nh * 2 + u) * 16 + lm;
#pragma unroll
      for (int r = 0; r < 4; ++r) {
        int o = (mg * 4 + a) * 16 + q * 4 + r;
        float v = fmaf(acc[a][u][r], invsh[o], invsh[O + o]);
        out[((size_t)(b * O + o)) * HWSZ + h * W + nn] = fmaxf(v, 0.0f);
      }
    }
  }
}

extern "C" void kernel_launch(void* const* d_in, const int* in_sizes, int n_in,
                              void* d_out, int out_size, void* d_ws, size_t ws_size,
                              hipStream_t stream) {
  const float* x        = (const float*)d_in[0];
  const float* w_off    = (const float*)d_in[1];
  const float* b_off    = (const float*)d_in[2];
  const float* weight   = (const float*)d_in[3];
  const float* bias     = (const float*)d_in[4];
  const float* gamma    = (const float*)d_in[5];
  const float* beta     = (const float*)d_in[6];
  const float* run_mean = (const float*)d_in[7];
  const float* run_var  = (const float*)d_in[8];
  float* out = (float*)d_out;

  // workspace layout (~21.65 MB)
  char* ws = (char*)d_ws;
  unsigned short* xt = (unsigned short*)ws;                    // 16777216 B
  float* om  = (float*)(ws + 16777216);                        // 3538944 B
  unsigned short* wbf = (unsigned short*)(ws + 20316160);      // 1179648 B
  unsigned short* wob = (unsigned short*)(ws + 21495808);      // 147456 B
  float* invsh = (float*)(ws + 21643264);                      // 2048 B

  {
    dim3 grid(NB, H, 2);
    transpose_x<<<grid, 256, 0, stream>>>(x, xt);
  }
  prep_weight<<<O * CK / 512, 256, 0, stream>>>(weight, wbf);
  prep_woff<<<32 * CK / 512, 256, 0, stream>>>(w_off, wob);
  prep_bn<<<1, 256, 0, stream>>>(bias, gamma, beta, run_mean, run_var, invsh);

  {
    dim3 grid(NB, H, 2);
    offset_mfma_kernel<<<grid, 256, 0, stream>>>(xt, wob, b_off, om);
  }
  {
    dim3 grid(NB, H);
    deform_mfma_kernel<<<grid, 512, 0, stream>>>(xt, om, wbf, invsh, out);
  }
}

// Round 7
// 208.724 us; speedup vs baseline: 10.1634x; 1.0181x over previous
//
#include <hip/hip_runtime.h>
#include <math.h>

#define H 64
#define W 64
#define C 256
#define O 256
#define CK 2304
#define NB 8
#define HWSZ 4096            // H*W

typedef __attribute__((ext_vector_type(8))) short short8;
typedef __attribute__((ext_vector_type(4))) float floatx4;
typedef __attribute__((ext_vector_type(4))) unsigned uintx4;

// swizzle giving uniform bank-group coverage in every 16-lane b128 phase
// for both the sampling-write map and the MFMA-read map
#define FSWZ(n) ((((n) & 3) << 1) | (((n) >> 2) & 1))

__device__ __forceinline__ unsigned short f2bf(float f) {
  unsigned u = __builtin_bit_cast(unsigned, f);
  unsigned r = (u + 0x7fffu + ((u >> 16) & 1u)) >> 16;
  return (unsigned short)r;
}
__device__ __forceinline__ float lo2f(unsigned u) {
  return __builtin_bit_cast(float, u << 16);
}
__device__ __forceinline__ float hi2f(unsigned u) {
  return __builtin_bit_cast(float, u & 0xffff0000u);
}
// pack two fp32 -> bf16 pair, round-half-up (1 add+shift / add+and per elem)
__device__ __forceinline__ unsigned pk2bf(float v0, float v1) {
  unsigned a = __builtin_bit_cast(unsigned, v0);
  unsigned b = __builtin_bit_cast(unsigned, v1);
  return ((a + 0x8000u) >> 16) | ((b + 0x8000u) & 0xffff0000u);
}

// ---------------- Kernel T: x NCHW fp32 -> NHWC bf16 ---------------------
__global__ __launch_bounds__(256) void transpose_x(
    const float* __restrict__ x, unsigned short* __restrict__ xt) {
  __shared__ unsigned tile[64 * 65];      // [c-pair][xx], stride 65
  int b = blockIdx.x, y = blockIdx.y, cg = blockIdx.z;
  int tid = threadIdx.x;
  const float* xb = x + ((size_t)b * C + cg * 128) * HWSZ + y * W;
#pragma unroll 4
  for (int it = 0; it < 16; ++it) {
    int e = tid + 256 * it;
    int xx = e & 63;
    int cp = e >> 6;                      // local c-pair 0..63
    float f0 = xb[(size_t)(2 * cp) * HWSZ + xx];
    float f1 = xb[(size_t)(2 * cp + 1) * HWSZ + xx];
    tile[cp * 65 + xx] = (unsigned)f2bf(f0) | ((unsigned)f2bf(f1) << 16);
  }
  __syncthreads();
  unsigned short* xo = xt + ((size_t)(b * 64 + y) << 14) + cg * 128;
#pragma unroll
  for (int it = 0; it < 4; ++it) {
    int e = tid + 256 * it;
    int cq = e & 15;
    int xx = e >> 4;
    unsigned u0 = tile[(cq * 4 + 0) * 65 + xx];
    unsigned u1 = tile[(cq * 4 + 1) * 65 + xx];
    unsigned u2 = tile[(cq * 4 + 2) * 65 + xx];
    unsigned u3 = tile[(cq * 4 + 3) * 65 + xx];
    uint4 v = {u0, u1, u2, u3};
    *reinterpret_cast<uint4*>(xo + (xx << 8) + (cq << 3)) = v;
  }
}

// ---------------- Prep A: main weight fp32 -> bf16 MFMA-A fragments -------
__global__ __launch_bounds__(256) void prep_weight(
    const float* __restrict__ weight, unsigned short* __restrict__ wb) {
  int d0 = (blockIdx.x * 256 + threadIdx.x) * 2;
  unsigned short v[2];
#pragma unroll
  for (int e = 0; e < 2; ++e) {
    int d = d0 + e;
    int j = d & 7;
    int lane = (d >> 3) & 63;
    int mt = (d >> 9) & 15;
    int ks = d >> 13;
    int o = mt * 16 + (lane & 15);
    int kn = ks * 32 + (lane >> 4) * 8 + j;
    int tap = kn >> 8;
    int c = kn & 255;
    v[e] = f2bf(weight[o * CK + c * 9 + tap]);
  }
  *reinterpret_cast<unsigned*>(wb + d0) =
      (unsigned)v[0] | ((unsigned)v[1] << 16);
}

// ---------------- Prep A2: offset weight -> bf16 A fragments (M pad 32) ---
__global__ __launch_bounds__(256) void prep_woff(
    const float* __restrict__ w_off, unsigned short* __restrict__ wob) {
  int d0 = (blockIdx.x * 256 + threadIdx.x) * 2;
  unsigned short v[2];
#pragma unroll
  for (int e = 0; e < 2; ++e) {
    int d = d0 + e;
    int j = d & 7;
    int lane = (d >> 3) & 63;
    int mt = (d >> 9) & 1;
    int ks = d >> 10;
    int o = mt * 16 + (lane & 15);
    int kn = ks * 32 + (lane >> 4) * 8 + j;
    int tap = kn >> 8;
    int c = kn & 255;
    v[e] = (o < 27) ? f2bf(w_off[o * CK + c * 9 + tap]) : (unsigned short)0;
  }
  *reinterpret_cast<unsigned*>(wob + d0) =
      (unsigned)v[0] | ((unsigned)v[1] << 16);
}

// ---------------- Prep B: folded BN scale/shift --------------------------
__global__ __launch_bounds__(256) void prep_bn(
    const float* __restrict__ bias, const float* __restrict__ gamma,
    const float* __restrict__ beta, const float* __restrict__ run_mean,
    const float* __restrict__ run_var, float* __restrict__ invsh) {
  int o = threadIdx.x;
  float inv = gamma[o] * rsqrtf(run_var[o] + 1e-5f);
  invsh[o] = inv;
  invsh[O + o] = beta[o] + (bias[o] - run_mean[o]) * inv;
}

// ---------------- Fused kernel: offset conv + deform sample + GEMM + BN ---
// grid (b, h), 512 threads (8 waves).  Block = row h: 64 px x 256 out.
// Phase A: offset conv (27x64) via MFMA, B-frags direct from xt -> sm_om.
// Phase B: bilinear tables, sample to LDS cols, main MFMA, BN+ReLU.
__global__ __launch_bounds__(512, 4) void deform_mfma_kernel(
    const unsigned short* __restrict__ xt, const unsigned short* __restrict__ wob,
    const float* __restrict__ b_off, const unsigned short* __restrict__ wb,
    const float* __restrict__ invsh, float* __restrict__ out) {
  __shared__ short cols[64 * 256];       // 32 KB, FSWZ-swizzled
  __shared__ float sm_om[27 * 64];       // offset-conv result for this row
  __shared__ int sbase[576];
  __shared__ float s00[576], s01[576], s10[576], s11[576];

  int tid = threadIdx.x;
  int lane = tid & 63;
  int wvid = tid >> 6;                   // 0..7
  int q = lane >> 4;
  int lm = lane & 15;
  int b = blockIdx.x;
  int h = blockIdx.y;
  const unsigned short* xtb = xt + ((size_t)b << 20);

  // ======== Phase A: offset conv for this row (wave = 1 m-tile x 1 n-tile)
  {
    int mt = wvid & 1;                   // m-tile 0..1 (outs 0..31)
    int nt = wvid >> 1;                  // n-tile 0..3 (px group)
    floatx4 acc0 = (floatx4){0.f, 0.f, 0.f, 0.f};
    int px = nt * 16 + lm;
    for (int tap = 0; tap < 9; ++tap) {
      int yy = h - 1 + tap / 3;
      int xx = px - 1 + tap % 3;
      bool v = (yy >= 0) && (yy < H) && (xx >= 0) && (xx < W);
      const unsigned short* bp =
          xtb + ((((yy & 63) << 6) + (xx & 63)) << 8) + q * 8;
#pragma unroll
      for (int s = 0; s < 8; ++s) {
        int ks = tap * 8 + s;
        short8 bfrag;
        if (v)
          bfrag = *reinterpret_cast<const short8*>(bp + s * 32);
        else
          bfrag = (short8){0, 0, 0, 0, 0, 0, 0, 0};
        short8 afrag = *reinterpret_cast<const short8*>(
            wob + (((ks * 2 + mt) * 64 + lane) << 3));
        acc0 = __builtin_amdgcn_mfma_f32_16x16x32_bf16(afrag, bfrag, acc0, 0, 0, 0);
      }
    }
#pragma unroll
    for (int r = 0; r < 4; ++r) {
      int o = mt * 16 + q * 4 + r;
      if (o < 27) sm_om[o * 64 + px] = acc0[r] + b_off[o];
    }
  }
  __syncthreads();

  // ======== Phase A2: separable clamp-swap bilinear tables (9 taps x 64 px)
  for (int e = tid; e < 576; e += 512) {
    int n = e & 63;
    int k = e >> 6;
    float oy = sm_om[k * 64 + n];
    float ox = sm_om[(9 + k) * 64 + n];
    float mv = sm_om[(18 + k) * 64 + n];
    float m = 1.0f / (1.0f + __expf(-mv));
    float py = (float)(h - 1 + k / 3) + oy;
    float px = (float)(n - 1 + k % 3) + ox;
    float yf = floorf(py), xf = floorf(px);
    int y0 = (int)yf, x0 = (int)xf;
    float fy = py - yf, fx = px - xf;
    float r0, r1; int yl;
    if (y0 >= 0 && y0 <= H - 2)      { yl = y0;    r0 = 1.f - fy; r1 = fy;       }
    else if (y0 == -1)               { yl = 0;     r0 = fy;       r1 = 0.f;      }
    else if (y0 == H - 1)            { yl = H - 2; r0 = 0.f;      r1 = 1.f - fy; }
    else                             { yl = 0;     r0 = 0.f;      r1 = 0.f;      }
    float c0, c1; int xl;
    if (x0 >= 0 && x0 <= W - 2)      { xl = x0;    c0 = 1.f - fx; c1 = fx;       }
    else if (x0 == -1)               { xl = 0;     c0 = fx;       c1 = 0.f;      }
    else if (x0 == W - 1)            { xl = W - 2; c0 = 0.f;      c1 = 1.f - fx; }
    else                             { xl = 0;     c0 = 0.f;      c1 = 0.f;      }
    r0 *= m; r1 *= m;
    sbase[e] = ((yl << 6) + xl) << 8;
    s00[e] = r0 * c0; s01[e] = r0 * c1;
    s10[e] = r1 * c0; s11[e] = r1 * c1;
  }
  __syncthreads();

  // ======== Phase B: main deformable GEMM
  floatx4 acc[4][2];                     // [m within group][n within half]
  int mg = wvid >> 1;                    // m-group: m-tiles mg*4..mg*4+3
  int nh = wvid & 1;                     // n-half: n-tiles nh*2, nh*2+1
#pragma unroll
  for (int a = 0; a < 4; ++a)
#pragma unroll
    for (int u = 0; u < 2; ++u) acc[a][u] = (floatx4){0.f, 0.f, 0.f, 0.f};

  int sn = tid >> 3;        // pixel 0..63
  int scb = tid & 7;        // c-block low bits

  for (int tap = 0; tap < 9; ++tap) {
    if (tap) __syncthreads();
    // ---- sampling: 4 coalesced corner loads per c-block of 8 ----
    {
      int ei = tap * 64 + sn;
      int base = sbase[ei];
      float w00 = s00[ei], w01 = s01[ei], w10 = s10[ei], w11 = s11[ei];
      const unsigned short* p = xtb + base;
#pragma unroll
      for (int i = 0; i < 4; ++i) {
        int cbw = (i << 3) | scb;
        int co = cbw << 3;
        uintx4 u00 = *reinterpret_cast<const uintx4*>(p + co);
        uintx4 u01 = *reinterpret_cast<const uintx4*>(p + 256 + co);
        uintx4 u10 = *reinterpret_cast<const uintx4*>(p + 16384 + co);
        uintx4 u11 = *reinterpret_cast<const uintx4*>(p + 16640 + co);
        uintx4 res;
#pragma unroll
        for (int jd = 0; jd < 4; ++jd) {
          float v0 = fmaf(w00, lo2f(u00[jd]),
                     fmaf(w01, lo2f(u01[jd]),
                     fmaf(w10, lo2f(u10[jd]), w11 * lo2f(u11[jd]))));
          float v1 = fmaf(w00, hi2f(u00[jd]),
                     fmaf(w01, hi2f(u01[jd]),
                     fmaf(w10, hi2f(u10[jd]), w11 * hi2f(u11[jd]))));
          res[jd] = pk2bf(v0, v1);
        }
        int pos = (cbw ^ FSWZ(sn)) & 31;
        *reinterpret_cast<uintx4*>(&cols[(sn << 8) + (pos << 3)]) = res;
      }
    }
    __syncthreads();

    // ---- MFMA: 8 k-steps, 4 m-tiles x 2 n-tiles per wave ----
#pragma unroll
    for (int s = 0; s < 8; ++s) {
      int ks = tap * 8 + s;
      short8 afrag[4];
#pragma unroll
      for (int a = 0; a < 4; ++a)
        afrag[a] = *reinterpret_cast<const short8*>(
            wb + (((ks * 16 + mg * 4 + a) * 64 + lane) << 3));
      short8 bfrag[2];
#pragma unroll
      for (int u = 0; u < 2; ++u) {
        int nn = (nh * 2 + u) * 16 + lm;
        int pos = ((s * 4 + q) ^ FSWZ(nn)) & 31;
        bfrag[u] = *reinterpret_cast<const short8*>(&cols[(nn << 8) + (pos << 3)]);
      }
#pragma unroll
      for (int a = 0; a < 4; ++a)
#pragma unroll
        for (int u = 0; u < 2; ++u)
          acc[a][u] = __builtin_amdgcn_mfma_f32_16x16x32_bf16(
              afrag[a], bfrag[u], acc[a][u], 0, 0, 0);
    }
  }

  // ---- epilogue: BN + ReLU + store ----
#pragma unroll
  for (int a = 0; a < 4; ++a) {
#pragma unroll
    for (int u = 0; u < 2; ++u) {
      int nn = (nh * 2 + u) * 16 + lm;
#pragma unroll
      for (int r = 0; r < 4; ++r) {
        int o = (mg * 4 + a) * 16 + q * 4 + r;
        float v = fmaf(acc[a][u][r], invsh[o], invsh[O + o]);
        out[((size_t)(b * O + o)) * HWSZ + h * W + nn] = fmaxf(v, 0.0f);
      }
    }
  }
}

extern "C" void kernel_launch(void* const* d_in, const int* in_sizes, int n_in,
                              void* d_out, int out_size, void* d_ws, size_t ws_size,
                              hipStream_t stream) {
  const float* x        = (const float*)d_in[0];
  const float* w_off    = (const float*)d_in[1];
  const float* b_off    = (const float*)d_in[2];
  const float* weight   = (const float*)d_in[3];
  const float* bias     = (const float*)d_in[4];
  const float* gamma    = (const float*)d_in[5];
  const float* beta     = (const float*)d_in[6];
  const float* run_mean = (const float*)d_in[7];
  const float* run_var  = (const float*)d_in[8];
  float* out = (float*)d_out;

  // workspace layout (~18.1 MB)
  char* ws = (char*)d_ws;
  unsigned short* xt = (unsigned short*)ws;                    // 16777216 B
  unsigned short* wbf = (unsigned short*)(ws + 16777216);      // 1179648 B
  unsigned short* wob = (unsigned short*)(ws + 17956864);      // 147456 B
  float* invsh = (float*)(ws + 18104320);                      // 2048 B

  {
    dim3 grid(NB, H, 2);
    transpose_x<<<grid, 256, 0, stream>>>(x, xt);
  }
  prep_weight<<<O * CK / 512, 256, 0, stream>>>(weight, wbf);
  prep_woff<<<32 * CK / 512, 256, 0, stream>>>(w_off, wob);
  prep_bn<<<1, 256, 0, stream>>>(bias, gamma, beta, run_mean, run_var, invsh);

  {
    dim3 grid(NB, H);
    deform_mfma_kernel<<<grid, 512, 0, stream>>>(xt, wob, b_off, wbf, invsh, out);
  }
}

// Round 8
// 192.505 us; speedup vs baseline: 11.0196x; 1.0843x over previous
//
#include <hip/hip_runtime.h>
#include <math.h>

#define H 64
#define W 64
#define C 256
#define O 256
#define CK 2304
#define NB 8
#define HWSZ 4096            // H*W

typedef __attribute__((ext_vector_type(8))) short short8;
typedef __attribute__((ext_vector_type(4))) float floatx4;
typedef __attribute__((ext_vector_type(4))) unsigned uintx4;

// swizzle giving uniform bank-group coverage in every 16-lane b128 phase
// for both the sampling-write map and the MFMA-read map
#define FSWZ(n) ((((n) & 3) << 1) | (((n) >> 2) & 1))

__device__ __forceinline__ unsigned short f2bf(float f) {
  unsigned u = __builtin_bit_cast(unsigned, f);
  unsigned r = (u + 0x7fffu + ((u >> 16) & 1u)) >> 16;
  return (unsigned short)r;
}
__device__ __forceinline__ float lo2f(unsigned u) {
  return __builtin_bit_cast(float, u << 16);
}
__device__ __forceinline__ float hi2f(unsigned u) {
  return __builtin_bit_cast(float, u & 0xffff0000u);
}
// pack two fp32 -> bf16 pair, round-half-up
__device__ __forceinline__ unsigned pk2bf(float v0, float v1) {
  unsigned a = __builtin_bit_cast(unsigned, v0);
  unsigned b = __builtin_bit_cast(unsigned, v1);
  return ((a + 0x8000u) >> 16) | ((b + 0x8000u) & 0xffff0000u);
}

// ---------------- prep_all: transpose + weight packs + BN, ONE launch -----
// region 0: bid <  1024 : transpose x NCHW fp32 -> NHWC bf16 (b = bid&7)
// region 1: bid < 1312 : prep main weight -> MFMA-A fragments (288 blocks)
// region 2: bid < 1348 : prep offset weight -> A fragments (36 blocks)
// region 3: bid == 1348: folded BN
__global__ __launch_bounds__(256) void prep_all(
    const float* __restrict__ x, const float* __restrict__ weight,
    const float* __restrict__ w_off, const float* __restrict__ bias,
    const float* __restrict__ gamma, const float* __restrict__ beta,
    const float* __restrict__ run_mean, const float* __restrict__ run_var,
    unsigned short* __restrict__ xt, unsigned short* __restrict__ wb,
    unsigned short* __restrict__ wob, float* __restrict__ invsh) {
  __shared__ unsigned tile[64 * 65];
  int bid = blockIdx.x;
  int tid = threadIdx.x;

  if (bid < 1024) {
    // ---- transpose: block = (b, y, cg-half of channels) ----
    int b = bid & 7;
    int t = bid >> 3;
    int y = t >> 1;
    int cg = t & 1;
    const float* xb = x + ((size_t)b * C + cg * 128) * HWSZ + y * W;
#pragma unroll
    for (int it = 0; it < 4; ++it) {
      int e = tid + 256 * it;              // (cp 0..63) x (xx4 0..15)
      int xx4 = e & 15;
      int cp = e >> 4;
      floatx4 f0 = *reinterpret_cast<const floatx4*>(
          xb + (size_t)(2 * cp) * HWSZ + xx4 * 4);
      floatx4 f1 = *reinterpret_cast<const floatx4*>(
          xb + (size_t)(2 * cp + 1) * HWSZ + xx4 * 4);
#pragma unroll
      for (int k = 0; k < 4; ++k)
        tile[cp * 65 + xx4 * 4 + k] = pk2bf(f0[k], f1[k]);
    }
    __syncthreads();
    unsigned short* xo = xt + ((size_t)(b * 64 + y) << 14) + cg * 128;
#pragma unroll
    for (int it = 0; it < 4; ++it) {
      int e = tid + 256 * it;
      int cq = e & 15;
      int xx = e >> 4;
      unsigned u0 = tile[(cq * 4 + 0) * 65 + xx];
      unsigned u1 = tile[(cq * 4 + 1) * 65 + xx];
      unsigned u2 = tile[(cq * 4 + 2) * 65 + xx];
      unsigned u3 = tile[(cq * 4 + 3) * 65 + xx];
      uint4 v = {u0, u1, u2, u3};
      *reinterpret_cast<uint4*>(xo + (xx << 8) + (cq << 3)) = v;
    }
  } else if (bid < 1312) {
    // ---- prep main weight: 8 elems/thread, one b128 store ----
    int d0 = ((bid - 1024) * 256 + tid) * 8;
    int lane = (d0 >> 3) & 63;
    int mt = (d0 >> 9) & 15;
    int ks = d0 >> 13;
    int o = mt * 16 + (lane & 15);
    int kn0 = ks * 32 + (lane >> 4) * 8;
    int tap = kn0 >> 8;
    int c0 = kn0 & 255;
    const float* wsrc = weight + o * CK + c0 * 9 + tap;
    unsigned pk[4];
#pragma unroll
    for (int p = 0; p < 4; ++p)
      pk[p] = pk2bf(wsrc[(2 * p) * 9], wsrc[(2 * p + 1) * 9]);
    uint4 v = {pk[0], pk[1], pk[2], pk[3]};
    *reinterpret_cast<uint4*>(wb + d0) = v;
  } else if (bid < 1348) {
    // ---- prep offset weight (M padded 27->32) ----
    int d0 = ((bid - 1312) * 256 + tid) * 8;
    int lane = (d0 >> 3) & 63;
    int mt = (d0 >> 9) & 1;
    int ks = d0 >> 10;
    int o = mt * 16 + (lane & 15);
    int kn0 = ks * 32 + (lane >> 4) * 8;
    int tap = kn0 >> 8;
    int c0 = kn0 & 255;
    uint4 v;
    if (o < 27) {
      const float* wsrc = w_off + o * CK + c0 * 9 + tap;
      unsigned pk[4];
#pragma unroll
      for (int p = 0; p < 4; ++p)
        pk[p] = pk2bf(wsrc[(2 * p) * 9], wsrc[(2 * p + 1) * 9]);
      v = (uint4){pk[0], pk[1], pk[2], pk[3]};
    } else {
      v = (uint4){0, 0, 0, 0};
    }
    *reinterpret_cast<uint4*>(wob + d0) = v;
  } else {
    // ---- folded BN ----
    int o = tid;
    float inv = gamma[o] * rsqrtf(run_var[o] + 1e-5f);
    invsh[o] = inv;
    invsh[O + o] = beta[o] + (bias[o] - run_mean[o]) * inv;
  }
}

// ---------------- Fused kernel: offset conv + deform sample + GEMM + BN ---
// grid (b, h), 512 threads (8 waves).  Block = row h: 64 px x 256 out.
__global__ __launch_bounds__(512, 4) void deform_mfma_kernel(
    const unsigned short* __restrict__ xt, const unsigned short* __restrict__ wob,
    const float* __restrict__ b_off, const unsigned short* __restrict__ wb,
    const float* __restrict__ invsh, float* __restrict__ out) {
  __shared__ short cols[64 * 256];       // 32 KB, FSWZ-swizzled
  __shared__ float sm_om[27 * 64];       // offset-conv result for this row
  __shared__ int sbase[576];
  __shared__ float s00[576], s01[576], s10[576], s11[576];

  int tid = threadIdx.x;
  int lane = tid & 63;
  int wvid = tid >> 6;                   // 0..7
  int q = lane >> 4;
  int lm = lane & 15;
  int b = blockIdx.x;
  int h = blockIdx.y;
  const unsigned short* xtb = xt + ((size_t)b << 20);

  // ======== Phase A: offset conv, 4 active waves, wave = 1 mt x 2 nt
  if (wvid < 4) {
    int mt = wvid & 1;
    int nh = wvid >> 1;                  // px quarter-pair
    floatx4 a0[2];
    a0[0] = (floatx4){0.f, 0.f, 0.f, 0.f};
    a0[1] = (floatx4){0.f, 0.f, 0.f, 0.f};
    int pxu[2];
    pxu[0] = (nh * 2 + 0) * 16 + lm;
    pxu[1] = (nh * 2 + 1) * 16 + lm;
    for (int tap = 0; tap < 9; ++tap) {
      int yy = h - 1 + tap / 3;
      bool vy = (yy >= 0) && (yy < H);
      const unsigned short* bp[2];
      bool vv[2];
#pragma unroll
      for (int u = 0; u < 2; ++u) {
        int xx = pxu[u] - 1 + tap % 3;
        vv[u] = vy && (xx >= 0) && (xx < W);
        bp[u] = xtb + ((((yy & 63) << 6) + (xx & 63)) << 8) + q * 8;
      }
#pragma unroll
      for (int s = 0; s < 8; ++s) {
        int ks = tap * 8 + s;
        short8 afrag = *reinterpret_cast<const short8*>(
            wob + (((ks * 2 + mt) * 64 + lane) << 3));
#pragma unroll
        for (int u = 0; u < 2; ++u) {
          short8 bfrag;
          if (vv[u])
            bfrag = *reinterpret_cast<const short8*>(bp[u] + s * 32);
          else
            bfrag = (short8){0, 0, 0, 0, 0, 0, 0, 0};
          a0[u] = __builtin_amdgcn_mfma_f32_16x16x32_bf16(afrag, bfrag, a0[u], 0, 0, 0);
        }
      }
    }
#pragma unroll
    for (int u = 0; u < 2; ++u)
#pragma unroll
      for (int r = 0; r < 4; ++r) {
        int o = mt * 16 + q * 4 + r;
        if (o < 27) sm_om[o * 64 + pxu[u]] = a0[u][r] + b_off[o];
      }
  }
  __syncthreads();

  // ======== Phase A2: separable clamp-swap bilinear tables (9 taps x 64 px)
  for (int e = tid; e < 576; e += 512) {
    int n = e & 63;
    int k = e >> 6;
    float oy = sm_om[k * 64 + n];
    float ox = sm_om[(9 + k) * 64 + n];
    float mv = sm_om[(18 + k) * 64 + n];
    float m = 1.0f / (1.0f + __expf(-mv));
    float py = (float)(h - 1 + k / 3) + oy;
    float px = (float)(n - 1 + k % 3) + ox;
    float yf = floorf(py), xf = floorf(px);
    int y0 = (int)yf, x0 = (int)xf;
    float fy = py - yf, fx = px - xf;
    float r0, r1; int yl;
    if (y0 >= 0 && y0 <= H - 2)      { yl = y0;    r0 = 1.f - fy; r1 = fy;       }
    else if (y0 == -1)               { yl = 0;     r0 = fy;       r1 = 0.f;      }
    else if (y0 == H - 1)            { yl = H - 2; r0 = 0.f;      r1 = 1.f - fy; }
    else                             { yl = 0;     r0 = 0.f;      r1 = 0.f;      }
    float c0, c1; int xl;
    if (x0 >= 0 && x0 <= W - 2)      { xl = x0;    c0 = 1.f - fx; c1 = fx;       }
    else if (x0 == -1)               { xl = 0;     c0 = fx;       c1 = 0.f;      }
    else if (x0 == W - 1)            { xl = W - 2; c0 = 0.f;      c1 = 1.f - fx; }
    else                             { xl = 0;     c0 = 0.f;      c1 = 0.f;      }
    r0 *= m; r1 *= m;
    sbase[e] = ((yl << 6) + xl) << 8;
    s00[e] = r0 * c0; s01[e] = r0 * c1;
    s10[e] = r1 * c0; s11[e] = r1 * c1;
  }
  __syncthreads();

  // ======== Phase B: main deformable GEMM.  Wave = 2 m-tiles x 4 n-tiles
  // (each (ks, m-tile) A-fragment loaded by exactly one wave)
  floatx4 acc[2][4];                     // [m within pair][n-tile]
#pragma unroll
  for (int a = 0; a < 2; ++a)
#pragma unroll
    for (int u = 0; u < 4; ++u) acc[a][u] = (floatx4){0.f, 0.f, 0.f, 0.f};

  int sn = tid >> 3;        // pixel 0..63
  int scb = tid & 7;        // c-block low bits

  for (int tap = 0; tap < 9; ++tap) {
    if (tap) __syncthreads();
    // ---- sampling: 4 coalesced corner loads per c-block of 8 ----
    {
      int ei = tap * 64 + sn;
      int base = sbase[ei];
      float w00 = s00[ei], w01 = s01[ei], w10 = s10[ei], w11 = s11[ei];
      const unsigned short* p = xtb + base;
#pragma unroll
      for (int i = 0; i < 4; ++i) {
        int cbw = (i << 3) | scb;
        int co = cbw << 3;
        uintx4 u00 = *reinterpret_cast<const uintx4*>(p + co);
        uintx4 u01 = *reinterpret_cast<const uintx4*>(p + 256 + co);
        uintx4 u10 = *reinterpret_cast<const uintx4*>(p + 16384 + co);
        uintx4 u11 = *reinterpret_cast<const uintx4*>(p + 16640 + co);
        uintx4 res;
#pragma unroll
        for (int jd = 0; jd < 4; ++jd) {
          float v0 = fmaf(w00, lo2f(u00[jd]),
                     fmaf(w01, lo2f(u01[jd]),
                     fmaf(w10, lo2f(u10[jd]), w11 * lo2f(u11[jd]))));
          float v1 = fmaf(w00, hi2f(u00[jd]),
                     fmaf(w01, hi2f(u01[jd]),
                     fmaf(w10, hi2f(u10[jd]), w11 * hi2f(u11[jd]))));
          res[jd] = pk2bf(v0, v1);
        }
        int pos = (cbw ^ FSWZ(sn)) & 31;
        *reinterpret_cast<uintx4*>(&cols[(sn << 8) + (pos << 3)]) = res;
      }
    }
    __syncthreads();

    // ---- MFMA: 8 k-steps, 2 m-tiles x 4 n-tiles per wave ----
#pragma unroll
    for (int s = 0; s < 8; ++s) {
      int ks = tap * 8 + s;
      short8 afrag[2];
#pragma unroll
      for (int a = 0; a < 2; ++a)
        afrag[a] = *reinterpret_cast<const short8*>(
            wb + (((ks * 16 + wvid * 2 + a) * 64 + lane) << 3));
      short8 bfrag[4];
#pragma unroll
      for (int u = 0; u < 4; ++u) {
        int nn = u * 16 + lm;
        int pos = ((s * 4 + q) ^ FSWZ(nn)) & 31;
        bfrag[u] = *reinterpret_cast<const short8*>(&cols[(nn << 8) + (pos << 3)]);
      }
#pragma unroll
      for (int a = 0; a < 2; ++a)
#pragma unroll
        for (int u = 0; u < 4; ++u)
          acc[a][u] = __builtin_amdgcn_mfma_f32_16x16x32_bf16(
              afrag[a], bfrag[u], acc[a][u], 0, 0, 0);
    }
  }

  // ---- epilogue: BN + ReLU + store ----
#pragma unroll
  for (int a = 0; a < 2; ++a) {
#pragma unroll
    for (int u = 0; u < 4; ++u) {
      int nn = u * 16 + lm;
#pragma unroll
      for (int r = 0; r < 4; ++r) {
        int o = (wvid * 2 + a) * 16 + q * 4 + r;
        float v = fmaf(acc[a][u][r], invsh[o], invsh[O + o]);
        out[((size_t)(b * O + o)) * HWSZ + h * W + nn] = fmaxf(v, 0.0f);
      }
    }
  }
}

extern "C" void kernel_launch(void* const* d_in, const int* in_sizes, int n_in,
                              void* d_out, int out_size, void* d_ws, size_t ws_size,
                              hipStream_t stream) {
  const float* x        = (const float*)d_in[0];
  const float* w_off    = (const float*)d_in[1];
  const float* b_off    = (const float*)d_in[2];
  const float* weight   = (const float*)d_in[3];
  const float* bias     = (const float*)d_in[4];
  const float* gamma    = (const float*)d_in[5];
  const float* beta     = (const float*)d_in[6];
  const float* run_mean = (const float*)d_in[7];
  const float* run_var  = (const float*)d_in[8];
  float* out = (float*)d_out;

  // workspace layout (~18.1 MB)
  char* ws = (char*)d_ws;
  unsigned short* xt = (unsigned short*)ws;                    // 16777216 B
  unsigned short* wbf = (unsigned short*)(ws + 16777216);      // 1179648 B
  unsigned short* wob = (unsigned short*)(ws + 17956864);      // 147456 B
  float* invsh = (float*)(ws + 18104320);                      // 2048 B

  prep_all<<<1349, 256, 0, stream>>>(x, weight, w_off, bias, gamma, beta,
                                     run_mean, run_var, xt, wbf, wob, invsh);
  {
    dim3 grid(NB, H);
    deform_mfma_kernel<<<grid, 512, 0, stream>>>(xt, wob, b_off, wbf, invsh, out);
  }
}